// Round 1
// baseline (939.110 us; speedup 1.0000x reference)
//
#include <hip/hip_runtime.h>
#include <hip/hip_bf16.h>
#include <math.h>

#define N_NODES 50000
#define N_EDGES 800000
#define N_GRAPHS 64

// ---------------- workspace layout (bytes) ----------------
// C1: [50000][512] f32 = 102,400,000   (reused later: C2 [50000][256] at 0, H2 [50000][64] at 51.2M)
static constexpr size_t OFF_C1   = 0;
static constexpr size_t OFF_C2   = 0;           // overwrites C1 (C1 dead after edge1)
static constexpr size_t OFF_H2   = 51200000;    // within old C1 region, disjoint from C2
static constexpr size_t OFF_H1   = 102400000;   // 25,600,000
static constexpr size_t OFF_ESRC = 128000000;   // 3,200,000
static constexpr size_t OFF_OFFS = 131200000;   // 50001*4 -> 200,064
static constexpr size_t OFF_CURS = 131400064;   // 50000*4 (also used as hist)
static constexpr size_t OFF_WT1  = 131600128;   // 128*512*4 = 262,144
static constexpr size_t OFF_BC1  = 131862272;   // 512*4
static constexpr size_t OFF_WT2  = 131864320;   // 128*256*4 = 131,072
static constexpr size_t OFF_BC2  = 131995392;   // 256*4
static constexpr size_t OFF_SG   = 131996416;   // 64*4
static constexpr size_t OFF_EG   = 131996672;   // 64*4
static constexpr size_t OFF_PL   = 131996928;   // 64*64*4 = 16,384

// ---------------- weight prep: transpose + concat ----------------
__global__ void prep1_kernel(const float* __restrict__ wk, const float* __restrict__ bk,
                             const float* __restrict__ wq, const float* __restrict__ bq,
                             const float* __restrict__ wv, const float* __restrict__ bv,
                             const float* __restrict__ ws, const float* __restrict__ bs,
                             float* __restrict__ Wt, float* __restrict__ bcat) {
    int t = blockIdx.x * 256 + threadIdx.x;           // 65536 total
    if (t < 128 * 512) {
        int k = t >> 9, c = t & 511;
        int g = c >> 7, n = c & 127;
        const float* W = (g == 0) ? wk : (g == 1) ? wq : (g == 2) ? wv : ws;
        Wt[t] = W[n * 128 + k];                        // Wt[k][c]
    }
    if (t < 512) {
        int g = t >> 7, n = t & 127;
        const float* B = (g == 0) ? bk : (g == 1) ? bq : (g == 2) ? bv : bs;
        bcat[t] = B[n];
    }
}

__global__ void prep2_kernel(const float* __restrict__ wk, const float* __restrict__ bk,
                             const float* __restrict__ wq, const float* __restrict__ bq,
                             const float* __restrict__ wv, const float* __restrict__ bv,
                             const float* __restrict__ ws, const float* __restrict__ bs,
                             float* __restrict__ Wt, float* __restrict__ bcat) {
    int t = blockIdx.x * 256 + threadIdx.x;           // 32768 total
    if (t < 128 * 256) {
        int k = t >> 8, c = t & 255;
        int g = c >> 6, n = c & 63;
        const float* W = (g == 0) ? wk : (g == 1) ? wq : (g == 2) ? wv : ws;
        Wt[t] = W[n * 128 + k];                        // [64][128] row-major source
    }
    if (t < 256) {
        int g = t >> 6, n = t & 63;
        const float* B = (g == 0) ? bk : (g == 1) ? bq : (g == 2) ? bv : bs;
        bcat[t] = B[n];
    }
}

// ---------------- CSR build ----------------
__global__ void hist_kernel(const int* __restrict__ dst, int* __restrict__ hist) {
    int e = blockIdx.x * 256 + threadIdx.x;
    if (e < N_EDGES) atomicAdd(&hist[dst[e]], 1);
}

__global__ void scan_kernel(const int* __restrict__ hist, int* __restrict__ offs,
                            int* __restrict__ cursor, int n) {
    __shared__ int part[1024];
    int tid = threadIdx.x;
    int chunk = (n + 1023) >> 10;
    int base = tid * chunk;
    int s = 0;
    for (int i = 0; i < chunk; ++i) {
        int idx = base + i;
        if (idx < n) s += hist[idx];
    }
    part[tid] = s;
    __syncthreads();
    for (int d = 1; d < 1024; d <<= 1) {
        int v = (tid >= d) ? part[tid - d] : 0;
        __syncthreads();
        part[tid] += v;
        __syncthreads();
    }
    int run = (tid == 0) ? 0 : part[tid - 1];
    for (int i = 0; i < chunk; ++i) {
        int idx = base + i;
        if (idx < n) {
            int h = hist[idx];     // read before cursor write (hist may alias cursor)
            offs[idx] = run;
            cursor[idx] = run;
            run += h;
        }
    }
    if (tid == 0) offs[n] = part[1023];
}

__global__ void fill_kernel(const int* __restrict__ src, const int* __restrict__ dst,
                            int* __restrict__ cursor, int* __restrict__ esrc) {
    int e = blockIdx.x * 256 + threadIdx.x;
    if (e < N_EDGES) {
        int d = dst[e];
        int pos = atomicAdd(&cursor[d], 1);
        esrc[pos] = src[e];
    }
}

// ---------------- f32 GEMM: C[M,NCAT] = A[M,128] * Bt[128,NCAT] + bias ----------------
template <int NCAT>
__global__ __launch_bounds__(256, 2) void gemm_kernel(const float* __restrict__ A,
                                                      const float* __restrict__ Bt,
                                                      const float* __restrict__ bias,
                                                      float* __restrict__ C, int M) {
    __shared__ float As[128][68];    // [row][k_local], pitch 68 -> a-reads conflict-free
    __shared__ float Bs[64][132];    // [k_local][col], pitch 132 -> b-reads 2-way (free)
    const int tid = threadIdx.x;
    const int ty = tid >> 4, tx = tid & 15;
    const int row0 = blockIdx.x * 128;
    const int col0 = blockIdx.y * 128;

    float acc[8][8];
#pragma unroll
    for (int i = 0; i < 8; ++i)
#pragma unroll
        for (int j = 0; j < 8; ++j) acc[i][j] = 0.f;

    for (int k0 = 0; k0 < 128; k0 += 64) {
        __syncthreads();
        // stage A half-tile: 128 rows x 64 k
#pragma unroll
        for (int i = 0; i < 8; ++i) {
            int idx = i * 256 + tid;
            int r = idx >> 4, c4 = idx & 15;
            int gr = row0 + r;
            float4 v = make_float4(0.f, 0.f, 0.f, 0.f);
            if (gr < M) v = *(const float4*)&A[(size_t)gr * 128 + k0 + c4 * 4];
            *(float4*)&As[r][c4 * 4] = v;
        }
        // stage B half-tile: 64 k x 128 cols
#pragma unroll
        for (int i = 0; i < 8; ++i) {
            int idx = i * 256 + tid;
            int r = idx >> 5, c4 = idx & 31;
            float4 v = *(const float4*)&Bt[(size_t)(k0 + r) * NCAT + col0 + c4 * 4];
            *(float4*)&Bs[r][c4 * 4] = v;
        }
        __syncthreads();
#pragma unroll 4
        for (int k = 0; k < 64; ++k) {
            float a[8], b[8];
#pragma unroll
            for (int i = 0; i < 8; ++i) a[i] = As[16 * i + ty][k];
            float4 b0 = *(const float4*)&Bs[k][tx * 4];
            float4 b1 = *(const float4*)&Bs[k][64 + tx * 4];
            b[0] = b0.x; b[1] = b0.y; b[2] = b0.z; b[3] = b0.w;
            b[4] = b1.x; b[5] = b1.y; b[6] = b1.z; b[7] = b1.w;
#pragma unroll
            for (int i = 0; i < 8; ++i)
#pragma unroll
                for (int j = 0; j < 8; ++j) acc[i][j] += a[i] * b[j];
        }
    }
    float bcol[8];
#pragma unroll
    for (int j = 0; j < 4; ++j) {
        bcol[j]     = bias[col0 + tx * 4 + j];
        bcol[j + 4] = bias[col0 + 64 + tx * 4 + j];
    }
#pragma unroll
    for (int i = 0; i < 8; ++i) {
        int r = row0 + 16 * i + ty;
        if (r < M) {
            float4 o0, o1;
            o0.x = acc[i][0] + bcol[0]; o0.y = acc[i][1] + bcol[1];
            o0.z = acc[i][2] + bcol[2]; o0.w = acc[i][3] + bcol[3];
            o1.x = acc[i][4] + bcol[4]; o1.y = acc[i][5] + bcol[5];
            o1.z = acc[i][6] + bcol[6]; o1.w = acc[i][7] + bcol[7];
            *(float4*)&C[(size_t)r * NCAT + col0 + tx * 4] = o0;
            *(float4*)&C[(size_t)r * NCAT + col0 + 64 + tx * 4] = o1;
        }
    }
}

// ---------------- edge aggregation (gather mode), layer1: 128 ch ----------------
// C1 row: [K(0..127) | Q(128..255) | V(256..383) | S(384..511)]
__global__ __launch_bounds__(256) void edge1_kernel(const float* __restrict__ C1,
                                                    const int* __restrict__ offs,
                                                    const int* __restrict__ esrc,
                                                    float* __restrict__ H1) {
    int node = blockIdx.x * 4 + (threadIdx.x >> 6);
    if (node >= N_NODES) return;
    int lane = threadIdx.x & 63;
    const size_t rb = (size_t)node * 512;
    float2 k2 = *(const float2*)&C1[rb + lane * 2];
    float2 s2 = *(const float2*)&C1[rb + 384 + lane * 2];
    float ax = 0.f, ay = 0.f;
    int e0 = offs[node], e1 = offs[node + 1];
    for (int j = e0; j < e1; ++j) {
        int s = esrc[j];
        const size_t sb = (size_t)s * 512;
        float2 q2 = *(const float2*)&C1[sb + 128 + lane * 2];
        float2 v2 = *(const float2*)&C1[sb + 256 + lane * 2];
        float gx = 1.f / (1.f + __expf(-(k2.x + q2.x)));
        float gy = 1.f / (1.f + __expf(-(k2.y + q2.y)));
        ax += gx * v2.x;
        ay += gy * v2.y;
    }
    float rx = s2.x + ax, ry = s2.y + ay;
    float2 o;
    o.x = rx > 0.f ? rx : 0.f;
    o.y = ry > 0.f ? ry : 0.f;
    *(float2*)&H1[(size_t)node * 128 + lane * 2] = o;
}

// layer2: 64 ch, C2 row: [K(0..63) | Q(64..127) | V(128..191) | S(192..255)]
__global__ __launch_bounds__(256) void edge2_kernel(const float* __restrict__ C2,
                                                    const int* __restrict__ offs,
                                                    const int* __restrict__ esrc,
                                                    float* __restrict__ H2) {
    int node = blockIdx.x * 4 + (threadIdx.x >> 6);
    if (node >= N_NODES) return;
    int lane = threadIdx.x & 63;
    const size_t rb = (size_t)node * 256;
    float k1 = C2[rb + lane];
    float s1 = C2[rb + 192 + lane];
    float a = 0.f;
    int e0 = offs[node], e1 = offs[node + 1];
    for (int j = e0; j < e1; ++j) {
        int s = esrc[j];
        const size_t sb = (size_t)s * 256;
        float q = C2[sb + 64 + lane];
        float v = C2[sb + 128 + lane];
        float g = 1.f / (1.f + __expf(-(k1 + q)));
        a += g * v;
    }
    float r = s1 + a;
    H2[(size_t)node * 64 + lane] = r > 0.f ? r : 0.f;
}

// ---------------- pooling ----------------
__global__ void bounds_kernel(const int* __restrict__ batch, int* __restrict__ sg,
                              int* __restrict__ eg) {
    int n = blockIdx.x * 256 + threadIdx.x;
    if (n >= N_NODES) return;
    int b = batch[n];
    atomicMin(&sg[b], n);
    atomicMax(&eg[b], n);
}

__global__ void pool_kernel(const float* __restrict__ H2, const int* __restrict__ sg,
                            const int* __restrict__ eg, float* __restrict__ pooled) {
    int g = blockIdx.x;
    int s = sg[g], e = eg[g];
    int ch = threadIdx.x & 63, sub = threadIdx.x >> 6;
    float acc = 0.f;
    for (int n = s + sub; n <= e; n += 4) acc += H2[(size_t)n * 64 + ch];
    __shared__ float red[4][64];
    red[sub][ch] = acc;
    __syncthreads();
    if (sub == 0) {
        float v = red[0][ch] + red[1][ch] + red[2][ch] + red[3][ch];
        int cnt = e - s + 1;
        if (cnt < 1) cnt = 1;
        pooled[g * 64 + ch] = v / (float)cnt;
    }
}

__global__ void fc_kernel(const float* __restrict__ pooled, const float* __restrict__ wfc,
                          const float* __restrict__ bfc, float* __restrict__ out) {
    int t = threadIdx.x;          // 128
    int g = t >> 1, c = t & 1;
    float s = bfc[c];
#pragma unroll
    for (int i = 0; i < 64; ++i) s += pooled[g * 64 + i] * wfc[c * 64 + i];
    out[g * 2 + c] = s;
}

// ---------------- launch ----------------
extern "C" void kernel_launch(void* const* d_in, const int* in_sizes, int n_in,
                              void* d_out, int out_size, void* d_ws, size_t ws_size,
                              hipStream_t stream) {
    (void)in_sizes; (void)n_in; (void)out_size; (void)ws_size;
    const float* x    = (const float*)d_in[0];
    const int*   ei   = (const int*)d_in[1];
    const int*   batch= (const int*)d_in[2];
    const float* w1k = (const float*)d_in[3];  const float* b1k = (const float*)d_in[4];
    const float* w1q = (const float*)d_in[5];  const float* b1q = (const float*)d_in[6];
    const float* w1v = (const float*)d_in[7];  const float* b1v = (const float*)d_in[8];
    const float* w1s = (const float*)d_in[9];  const float* b1s = (const float*)d_in[10];
    const float* w2k = (const float*)d_in[11]; const float* b2k = (const float*)d_in[12];
    const float* w2q = (const float*)d_in[13]; const float* b2q = (const float*)d_in[14];
    const float* w2v = (const float*)d_in[15]; const float* b2v = (const float*)d_in[16];
    const float* w2s = (const float*)d_in[17]; const float* b2s = (const float*)d_in[18];
    const float* wfc = (const float*)d_in[19]; const float* bfc = (const float*)d_in[20];
    float* out = (float*)d_out;

    char* ws = (char*)d_ws;
    float* C1   = (float*)(ws + OFF_C1);
    float* C2   = (float*)(ws + OFF_C2);
    float* H1   = (float*)(ws + OFF_H1);
    float* H2   = (float*)(ws + OFF_H2);
    int*   esrc = (int*)(ws + OFF_ESRC);
    int*   offs = (int*)(ws + OFF_OFFS);
    int*   curs = (int*)(ws + OFF_CURS);
    float* Wt1  = (float*)(ws + OFF_WT1);
    float* bc1  = (float*)(ws + OFF_BC1);
    float* Wt2  = (float*)(ws + OFF_WT2);
    float* bc2  = (float*)(ws + OFF_BC2);
    int*   sg   = (int*)(ws + OFF_SG);
    int*   eg   = (int*)(ws + OFF_EG);
    float* pl   = (float*)(ws + OFF_PL);

    const int* src = ei;
    const int* dst = ei + N_EDGES;

    // weight prep
    prep1_kernel<<<256, 256, 0, stream>>>(w1k, b1k, w1q, b1q, w1v, b1v, w1s, b1s, Wt1, bc1);
    prep2_kernel<<<128, 256, 0, stream>>>(w2k, b2k, w2q, b2q, w2v, b2v, w2s, b2s, Wt2, bc2);

    // CSR build (by dst)
    hipMemsetAsync(curs, 0, N_NODES * sizeof(int), stream);
    hist_kernel<<<(N_EDGES + 255) / 256, 256, 0, stream>>>(dst, curs);
    scan_kernel<<<1, 1024, 0, stream>>>(curs, offs, curs, N_NODES);
    fill_kernel<<<(N_EDGES + 255) / 256, 256, 0, stream>>>(src, dst, curs, esrc);

    // layer 1
    gemm_kernel<512><<<dim3(391, 4), 256, 0, stream>>>(x, Wt1, bc1, C1, N_NODES);
    edge1_kernel<<<12500, 256, 0, stream>>>(C1, offs, esrc, H1);

    // layer 2
    gemm_kernel<256><<<dim3(391, 2), 256, 0, stream>>>(H1, Wt2, bc2, C2, N_NODES);
    edge2_kernel<<<12500, 256, 0, stream>>>(C2, offs, esrc, H2);

    // pooling + fc
    hipMemsetAsync(sg, 0x7f, N_GRAPHS * sizeof(int), stream);
    hipMemsetAsync(eg, 0x80, N_GRAPHS * sizeof(int), stream);
    bounds_kernel<<<(N_NODES + 255) / 256, 256, 0, stream>>>(batch, sg, eg);
    pool_kernel<<<N_GRAPHS, 256, 0, stream>>>(H2, sg, eg, pl);
    fc_kernel<<<1, 128, 0, stream>>>(pl, wfc, bfc, out);
}

// Round 2
// 637.532 us; speedup vs baseline: 1.4730x; 1.4730x over previous
//
#include <hip/hip_runtime.h>
#include <hip/hip_bf16.h>
#include <math.h>

#define N_NODES 50000
#define N_EDGES 800000
#define N_GRAPHS 64

// ---------------- workspace layout (bytes) ----------------
static constexpr size_t OFF_C1   = 0;
static constexpr size_t OFF_C2   = 0;           // overwrites C1 (C1 dead after edge1)
static constexpr size_t OFF_H2   = 51200000;    // within old C1 region, disjoint from C2
static constexpr size_t OFF_H1   = 102400000;   // 25,600,000
static constexpr size_t OFF_ESRC = 128000000;   // 3,200,000
static constexpr size_t OFF_OFFS = 131200000;   // 50001*4 -> 200,064
static constexpr size_t OFF_CURS = 131400064;   // 50000*4 (also used as hist)
static constexpr size_t OFF_WT1  = 131600128;   // 128*512*4 = 262,144
static constexpr size_t OFF_BC1  = 131862272;   // 512*4
static constexpr size_t OFF_WT2  = 131864320;   // 128*256*4 = 131,072
static constexpr size_t OFF_BC2  = 131995392;   // 256*4
static constexpr size_t OFF_SG   = 131996416;   // 64*4
static constexpr size_t OFF_EG   = 131996672;   // 64*4
static constexpr size_t OFF_PL   = 131996928;   // 64*64*4 = 16,384

// ---------------- weight prep: transpose + concat ----------------
__global__ void prep1_kernel(const float* __restrict__ wk, const float* __restrict__ bk,
                             const float* __restrict__ wq, const float* __restrict__ bq,
                             const float* __restrict__ wv, const float* __restrict__ bv,
                             const float* __restrict__ ws, const float* __restrict__ bs,
                             float* __restrict__ Wt, float* __restrict__ bcat) {
    int t = blockIdx.x * 256 + threadIdx.x;           // 65536 total
    if (t < 128 * 512) {
        int k = t >> 9, c = t & 511;
        int g = c >> 7, n = c & 127;
        const float* W = (g == 0) ? wk : (g == 1) ? wq : (g == 2) ? wv : ws;
        Wt[t] = W[n * 128 + k];                        // Wt[k][c]
    }
    if (t < 512) {
        int g = t >> 7, n = t & 127;
        const float* B = (g == 0) ? bk : (g == 1) ? bq : (g == 2) ? bv : bs;
        bcat[t] = B[n];
    }
}

__global__ void prep2_kernel(const float* __restrict__ wk, const float* __restrict__ bk,
                             const float* __restrict__ wq, const float* __restrict__ bq,
                             const float* __restrict__ wv, const float* __restrict__ bv,
                             const float* __restrict__ ws, const float* __restrict__ bs,
                             float* __restrict__ Wt, float* __restrict__ bcat) {
    int t = blockIdx.x * 256 + threadIdx.x;           // 32768 total
    if (t < 128 * 256) {
        int k = t >> 8, c = t & 255;
        int g = c >> 6, n = c & 63;
        const float* W = (g == 0) ? wk : (g == 1) ? wq : (g == 2) ? wv : ws;
        Wt[t] = W[n * 128 + k];
    }
    if (t < 256) {
        int g = t >> 6, n = t & 63;
        const float* B = (g == 0) ? bk : (g == 1) ? bq : (g == 2) ? bv : bs;
        bcat[t] = B[n];
    }
}

// ---------------- CSR build ----------------
__global__ void hist_kernel(const int* __restrict__ dst, int* __restrict__ hist) {
    int e = blockIdx.x * 256 + threadIdx.x;
    if (e < N_EDGES) atomicAdd(&hist[dst[e]], 1);
}

__global__ void scan_kernel(const int* __restrict__ hist, int* __restrict__ offs,
                            int* __restrict__ cursor, int n) {
    __shared__ int part[1024];
    int tid = threadIdx.x;
    int chunk = (n + 1023) >> 10;
    int base = tid * chunk;
    int s = 0;
    for (int i = 0; i < chunk; ++i) {
        int idx = base + i;
        if (idx < n) s += hist[idx];
    }
    part[tid] = s;
    __syncthreads();
    for (int d = 1; d < 1024; d <<= 1) {
        int v = (tid >= d) ? part[tid - d] : 0;
        __syncthreads();
        part[tid] += v;
        __syncthreads();
    }
    int run = (tid == 0) ? 0 : part[tid - 1];
    for (int i = 0; i < chunk; ++i) {
        int idx = base + i;
        if (idx < n) {
            int h = hist[idx];     // read before cursor write (hist may alias cursor)
            offs[idx] = run;
            cursor[idx] = run;
            run += h;
        }
    }
    if (tid == 0) offs[n] = part[1023];
}

__global__ void fill_kernel(const int* __restrict__ src, const int* __restrict__ dst,
                            int* __restrict__ cursor, int* __restrict__ esrc) {
    int e = blockIdx.x * 256 + threadIdx.x;
    if (e < N_EDGES) {
        int d = dst[e];
        int pos = atomicAdd(&cursor[d], 1);
        esrc[pos] = src[e];
    }
}

// ---------------- f32 GEMM: C[M,NCAT] = A[M,128] * Bt[128,NCAT] + bias ----------------
template <int NCAT>
__global__ __launch_bounds__(256, 2) void gemm_kernel(const float* __restrict__ A,
                                                      const float* __restrict__ Bt,
                                                      const float* __restrict__ bias,
                                                      float* __restrict__ C, int M) {
    __shared__ float As[128][68];
    __shared__ float Bs[64][132];
    const int tid = threadIdx.x;
    const int ty = tid >> 4, tx = tid & 15;
    const int row0 = blockIdx.x * 128;
    const int col0 = blockIdx.y * 128;

    float acc[8][8];
#pragma unroll
    for (int i = 0; i < 8; ++i)
#pragma unroll
        for (int j = 0; j < 8; ++j) acc[i][j] = 0.f;

    for (int k0 = 0; k0 < 128; k0 += 64) {
        __syncthreads();
#pragma unroll
        for (int i = 0; i < 8; ++i) {
            int idx = i * 256 + tid;
            int r = idx >> 4, c4 = idx & 15;
            int gr = row0 + r;
            float4 v = make_float4(0.f, 0.f, 0.f, 0.f);
            if (gr < M) v = *(const float4*)&A[(size_t)gr * 128 + k0 + c4 * 4];
            *(float4*)&As[r][c4 * 4] = v;
        }
#pragma unroll
        for (int i = 0; i < 8; ++i) {
            int idx = i * 256 + tid;
            int r = idx >> 5, c4 = idx & 31;
            float4 v = *(const float4*)&Bt[(size_t)(k0 + r) * NCAT + col0 + c4 * 4];
            *(float4*)&Bs[r][c4 * 4] = v;
        }
        __syncthreads();
#pragma unroll 4
        for (int k = 0; k < 64; ++k) {
            float a[8], b[8];
#pragma unroll
            for (int i = 0; i < 8; ++i) a[i] = As[16 * i + ty][k];
            float4 b0 = *(const float4*)&Bs[k][tx * 4];
            float4 b1 = *(const float4*)&Bs[k][64 + tx * 4];
            b[0] = b0.x; b[1] = b0.y; b[2] = b0.z; b[3] = b0.w;
            b[4] = b1.x; b[5] = b1.y; b[6] = b1.z; b[7] = b1.w;
#pragma unroll
            for (int i = 0; i < 8; ++i)
#pragma unroll
                for (int j = 0; j < 8; ++j) acc[i][j] += a[i] * b[j];
        }
    }
    float bcol[8];
#pragma unroll
    for (int j = 0; j < 4; ++j) {
        bcol[j]     = bias[col0 + tx * 4 + j];
        bcol[j + 4] = bias[col0 + 64 + tx * 4 + j];
    }
#pragma unroll
    for (int i = 0; i < 8; ++i) {
        int r = row0 + 16 * i + ty;
        if (r < M) {
            float4 o0, o1;
            o0.x = acc[i][0] + bcol[0]; o0.y = acc[i][1] + bcol[1];
            o0.z = acc[i][2] + bcol[2]; o0.w = acc[i][3] + bcol[3];
            o1.x = acc[i][4] + bcol[4]; o1.y = acc[i][5] + bcol[5];
            o1.z = acc[i][6] + bcol[6]; o1.w = acc[i][7] + bcol[7];
            *(float4*)&C[(size_t)r * NCAT + col0 + tx * 4] = o0;
            *(float4*)&C[(size_t)r * NCAT + col0 + 64 + tx * 4] = o1;
        }
    }
}

// ---------------- edge aggregation (gather mode), layer1: 128 ch ----------------
// C1 row: [K(0..127) | Q(128..255) | V(256..383) | S(384..511)]
__global__ __launch_bounds__(256) void edge1_kernel(const float* __restrict__ C1,
                                                    const int* __restrict__ offs,
                                                    const int* __restrict__ esrc,
                                                    float* __restrict__ H1) {
    int node = blockIdx.x * 4 + (threadIdx.x >> 6);
    if (node >= N_NODES) return;
    int lane = threadIdx.x & 63;
    const size_t rb = (size_t)node * 512;
    float2 k2 = *(const float2*)&C1[rb + lane * 2];
    float2 s2 = *(const float2*)&C1[rb + 384 + lane * 2];
    float ax = 0.f, ay = 0.f;
    int e0 = offs[node], e1 = offs[node + 1];
    for (int j = e0; j < e1; ++j) {
        int s = esrc[j];
        const size_t sb = (size_t)s * 512;
        float2 q2 = *(const float2*)&C1[sb + 128 + lane * 2];
        float2 v2 = *(const float2*)&C1[sb + 256 + lane * 2];
        float gx = 1.f / (1.f + __expf(-(k2.x + q2.x)));
        float gy = 1.f / (1.f + __expf(-(k2.y + q2.y)));
        ax += gx * v2.x;
        ay += gy * v2.y;
    }
    float rx = s2.x + ax, ry = s2.y + ay;
    float2 o;
    o.x = rx > 0.f ? rx : 0.f;
    o.y = ry > 0.f ? ry : 0.f;
    *(float2*)&H1[(size_t)node * 128 + lane * 2] = o;
}

// layer2: 64 ch, C2 row: [K(0..63) | Q(64..127) | V(128..191) | S(192..255)]
__global__ __launch_bounds__(256) void edge2_kernel(const float* __restrict__ C2,
                                                    const int* __restrict__ offs,
                                                    const int* __restrict__ esrc,
                                                    float* __restrict__ H2) {
    int node = blockIdx.x * 4 + (threadIdx.x >> 6);
    if (node >= N_NODES) return;
    int lane = threadIdx.x & 63;
    const size_t rb = (size_t)node * 256;
    float k1 = C2[rb + lane];
    float s1 = C2[rb + 192 + lane];
    float a = 0.f;
    int e0 = offs[node], e1 = offs[node + 1];
    for (int j = e0; j < e1; ++j) {
        int s = esrc[j];
        const size_t sb = (size_t)s * 256;
        float q = C2[sb + 64 + lane];
        float v = C2[sb + 128 + lane];
        float g = 1.f / (1.f + __expf(-(k1 + q)));
        a += g * v;
    }
    float r = s1 + a;
    H2[(size_t)node * 64 + lane] = r > 0.f ? r : 0.f;
}

// ---------------- pooling ----------------
// batch is SORTED -> graph bounds are run transitions; no atomics.
__global__ void bounds_kernel(const int* __restrict__ batch, int* __restrict__ sg,
                              int* __restrict__ eg) {
    int n = blockIdx.x * 256 + threadIdx.x;
    if (n >= N_NODES) return;
    int b = batch[n];
    if (n == 0) {
        sg[b] = 0;
    } else {
        int p = batch[n - 1];
        if (p != b) { sg[b] = n; eg[p] = n - 1; }
    }
    if (n == N_NODES - 1) eg[b] = N_NODES - 1;
}

__global__ void pool_kernel(const float* __restrict__ H2, const int* __restrict__ sg,
                            const int* __restrict__ eg, float* __restrict__ pooled) {
    int g = blockIdx.x;
    int s = sg[g], e = eg[g];
    int ch = threadIdx.x & 63, sub = threadIdx.x >> 6;
    float acc = 0.f;
    for (int n = s + sub; n <= e; n += 4) acc += H2[(size_t)n * 64 + ch];
    __shared__ float red[4][64];
    red[sub][ch] = acc;
    __syncthreads();
    if (sub == 0) {
        float v = red[0][ch] + red[1][ch] + red[2][ch] + red[3][ch];
        int cnt = e - s + 1;
        if (cnt < 1) cnt = 1;
        pooled[g * 64 + ch] = v / (float)cnt;
    }
}

__global__ void fc_kernel(const float* __restrict__ pooled, const float* __restrict__ wfc,
                          const float* __restrict__ bfc, float* __restrict__ out) {
    int t = threadIdx.x;          // 128
    int g = t >> 1, c = t & 1;
    float s = bfc[c];
#pragma unroll
    for (int i = 0; i < 64; ++i) s += pooled[g * 64 + i] * wfc[c * 64 + i];
    out[g * 2 + c] = s;
}

// ---------------- launch ----------------
extern "C" void kernel_launch(void* const* d_in, const int* in_sizes, int n_in,
                              void* d_out, int out_size, void* d_ws, size_t ws_size,
                              hipStream_t stream) {
    (void)in_sizes; (void)n_in; (void)out_size; (void)ws_size;
    const float* x    = (const float*)d_in[0];
    const int*   ei   = (const int*)d_in[1];
    const int*   batch= (const int*)d_in[2];
    const float* w1k = (const float*)d_in[3];  const float* b1k = (const float*)d_in[4];
    const float* w1q = (const float*)d_in[5];  const float* b1q = (const float*)d_in[6];
    const float* w1v = (const float*)d_in[7];  const float* b1v = (const float*)d_in[8];
    const float* w1s = (const float*)d_in[9];  const float* b1s = (const float*)d_in[10];
    const float* w2k = (const float*)d_in[11]; const float* b2k = (const float*)d_in[12];
    const float* w2q = (const float*)d_in[13]; const float* b2q = (const float*)d_in[14];
    const float* w2v = (const float*)d_in[15]; const float* b2v = (const float*)d_in[16];
    const float* w2s = (const float*)d_in[17]; const float* b2s = (const float*)d_in[18];
    const float* wfc = (const float*)d_in[19]; const float* bfc = (const float*)d_in[20];
    float* out = (float*)d_out;

    char* ws = (char*)d_ws;
    float* C1   = (float*)(ws + OFF_C1);
    float* C2   = (float*)(ws + OFF_C2);
    float* H1   = (float*)(ws + OFF_H1);
    float* H2   = (float*)(ws + OFF_H2);
    int*   esrc = (int*)(ws + OFF_ESRC);
    int*   offs = (int*)(ws + OFF_OFFS);
    int*   curs = (int*)(ws + OFF_CURS);
    float* Wt1  = (float*)(ws + OFF_WT1);
    float* bc1  = (float*)(ws + OFF_BC1);
    float* Wt2  = (float*)(ws + OFF_WT2);
    float* bc2  = (float*)(ws + OFF_BC2);
    int*   sg   = (int*)(ws + OFF_SG);
    int*   eg   = (int*)(ws + OFF_EG);
    float* pl   = (float*)(ws + OFF_PL);

    const int* src = ei;
    const int* dst = ei + N_EDGES;

    // weight prep
    prep1_kernel<<<256, 256, 0, stream>>>(w1k, b1k, w1q, b1q, w1v, b1v, w1s, b1s, Wt1, bc1);
    prep2_kernel<<<128, 256, 0, stream>>>(w2k, b2k, w2q, b2q, w2v, b2v, w2s, b2s, Wt2, bc2);

    // CSR build (by dst)
    hipMemsetAsync(curs, 0, N_NODES * sizeof(int), stream);
    hist_kernel<<<(N_EDGES + 255) / 256, 256, 0, stream>>>(dst, curs);
    scan_kernel<<<1, 1024, 0, stream>>>(curs, offs, curs, N_NODES);
    fill_kernel<<<(N_EDGES + 255) / 256, 256, 0, stream>>>(src, dst, curs, esrc);

    // layer 1
    gemm_kernel<512><<<dim3(391, 4), 256, 0, stream>>>(x, Wt1, bc1, C1, N_NODES);
    edge1_kernel<<<12500, 256, 0, stream>>>(C1, offs, esrc, H1);

    // layer 2
    gemm_kernel<256><<<dim3(391, 2), 256, 0, stream>>>(H1, Wt2, bc2, C2, N_NODES);
    edge2_kernel<<<12500, 256, 0, stream>>>(C2, offs, esrc, H2);

    // pooling + fc
    hipMemsetAsync(sg, 0x7f, N_GRAPHS * sizeof(int), stream);
    hipMemsetAsync(eg, 0x80, N_GRAPHS * sizeof(int), stream);
    bounds_kernel<<<(N_NODES + 255) / 256, 256, 0, stream>>>(batch, sg, eg);
    pool_kernel<<<N_GRAPHS, 256, 0, stream>>>(H2, sg, eg, pl);
    fc_kernel<<<1, 128, 0, stream>>>(pl, wfc, bfc, out);
}

// Round 3
// 506.780 us; speedup vs baseline: 1.8531x; 1.2580x over previous
//
#include <hip/hip_runtime.h>
#include <hip/hip_bf16.h>
#include <math.h>

#define N_NODES 50000
#define N_EDGES 800000
#define N_GRAPHS 64
#define SCAN_BLOCKS 196   // ceil(50000/256)

// ---------------- workspace layout (bytes) ----------------
static constexpr size_t OFF_K1   = 0;            // f32 [50000][128] = 25.6 MB
static constexpr size_t OFF_S1   = 25600000;     // f32 [50000][128]
static constexpr size_t OFF_QV1  = 51200000;     // bf16 [50000][256] interleaved q,v = 25.6 MB
static constexpr size_t OFF_H1   = 76800000;     // f32 [50000][128]
// layer2 overlays layer1 buffers (dead after edge1):
static constexpr size_t OFF_K2   = 0;            // f32 [50000][64] = 12.8 MB
static constexpr size_t OFF_S2   = 12800000;     // f32 [50000][64]
static constexpr size_t OFF_QV2  = 25600000;     // bf16 [50000][128] interleaved = 12.8 MB
static constexpr size_t OFF_H2   = 38400000;     // f32 [50000][64]
static constexpr size_t OFF_ESRC = 102400000;    // 3.2 MB
static constexpr size_t OFF_OFFS = 105600000;    // 50001*4
static constexpr size_t OFF_CURS = 105800064;    // 50000*4 (hist, then cursor)
static constexpr size_t OFF_WT1  = 106000064;    // 128*512*4
static constexpr size_t OFF_BC1  = 106262272;    // 512*4
static constexpr size_t OFF_WT2  = 106264320;    // 128*256*4
static constexpr size_t OFF_BC2  = 106395392;    // 256*4
static constexpr size_t OFF_SG   = 106396416;
static constexpr size_t OFF_EG   = 106396672;
static constexpr size_t OFF_PL   = 106396928;    // 64*64*4
static constexpr size_t OFF_BSUM = 106413312;    // 196*4
static constexpr size_t OFF_BBAS = 106414336;    // 256*4

__device__ inline float bfu2f(unsigned short u) {
    union { unsigned int i; float f; } w;
    w.i = ((unsigned int)u) << 16;
    return w.f;
}

// ---------------- weight prep: transpose + concat ----------------
__global__ void prep1_kernel(const float* __restrict__ wk, const float* __restrict__ bk,
                             const float* __restrict__ wq, const float* __restrict__ bq,
                             const float* __restrict__ wv, const float* __restrict__ bv,
                             const float* __restrict__ ws, const float* __restrict__ bs,
                             float* __restrict__ Wt, float* __restrict__ bcat) {
    int t = blockIdx.x * 256 + threadIdx.x;           // 65536 total
    if (t < 128 * 512) {
        int k = t >> 9, c = t & 511;
        int g = c >> 7, n = c & 127;
        const float* W = (g == 0) ? wk : (g == 1) ? wq : (g == 2) ? wv : ws;
        Wt[t] = W[n * 128 + k];                        // Wt[k][c]
    }
    if (t < 512) {
        int g = t >> 7, n = t & 127;
        const float* B = (g == 0) ? bk : (g == 1) ? bq : (g == 2) ? bv : bs;
        bcat[t] = B[n];
    }
}

__global__ void prep2_kernel(const float* __restrict__ wk, const float* __restrict__ bk,
                             const float* __restrict__ wq, const float* __restrict__ bq,
                             const float* __restrict__ wv, const float* __restrict__ bv,
                             const float* __restrict__ ws, const float* __restrict__ bs,
                             float* __restrict__ Wt, float* __restrict__ bcat) {
    int t = blockIdx.x * 256 + threadIdx.x;           // 32768 total
    if (t < 128 * 256) {
        int k = t >> 8, c = t & 255;
        int g = c >> 6, n = c & 63;
        const float* W = (g == 0) ? wk : (g == 1) ? wq : (g == 2) ? wv : ws;
        Wt[t] = W[n * 128 + k];
    }
    if (t < 256) {
        int g = t >> 6, n = t & 63;
        const float* B = (g == 0) ? bk : (g == 1) ? bq : (g == 2) ? bv : bs;
        bcat[t] = B[n];
    }
}

// ---------------- CSR build ----------------
__global__ void hist_kernel(const int* __restrict__ dst, int* __restrict__ hist) {
    int e = blockIdx.x * 256 + threadIdx.x;
    if (e < N_EDGES) atomicAdd(&hist[dst[e]], 1);
}

// hierarchical scan: per-block sums -> scan sums -> per-block exclusive + base
__global__ void bsum_kernel(const int* __restrict__ hist, int* __restrict__ bsum) {
    int t = threadIdx.x;
    int idx = blockIdx.x * 256 + t;
    __shared__ int sh[256];
    sh[t] = (idx < N_NODES) ? hist[idx] : 0;
    __syncthreads();
    for (int d = 128; d > 0; d >>= 1) {
        if (t < d) sh[t] += sh[t + d];
        __syncthreads();
    }
    if (t == 0) bsum[blockIdx.x] = sh[0];
}

__global__ void bscan_kernel(const int* __restrict__ bsum, int* __restrict__ bbase) {
    int t = threadIdx.x;   // 256
    __shared__ int sh[256];
    sh[t] = (t < SCAN_BLOCKS) ? bsum[t] : 0;
    __syncthreads();
    for (int d = 1; d < 256; d <<= 1) {
        int v = (t >= d) ? sh[t - d] : 0;
        __syncthreads();
        sh[t] += v;
        __syncthreads();
    }
    if (t < SCAN_BLOCKS) bbase[t] = (t == 0) ? 0 : sh[t - 1];
}

__global__ void offs_kernel(const int* __restrict__ hist, const int* __restrict__ bbase,
                            int* __restrict__ offs, int* __restrict__ cursor) {
    int t = threadIdx.x;
    int idx = blockIdx.x * 256 + t;
    int v = (idx < N_NODES) ? hist[idx] : 0;
    __shared__ int sh[256];
    sh[t] = v;
    __syncthreads();
    for (int d = 1; d < 256; d <<= 1) {
        int u = (t >= d) ? sh[t - d] : 0;
        __syncthreads();
        sh[t] += u;
        __syncthreads();
    }
    if (idx < N_NODES) {
        int o = bbase[blockIdx.x] + sh[t] - v;   // exclusive
        offs[idx] = o;
        cursor[idx] = o;                          // cursor aliases hist; per-index RAW only
    }
    if (idx == 0) offs[N_NODES] = N_EDGES;
}

__global__ void fill_kernel(const int* __restrict__ src, const int* __restrict__ dst,
                            int* __restrict__ cursor, int* __restrict__ esrc) {
    int e = blockIdx.x * 256 + threadIdx.x;
    if (e < N_EDGES) {
        int d = dst[e];
        int pos = atomicAdd(&cursor[d], 1);
        esrc[pos] = src[e];
    }
}

// ---------------- f32 GEMM with split epilogue ----------------
// LAYER=1: NCAT=512, blockIdx.y: 0=K(f32),1=Q(bf16,par0),2=V(bf16,par1),3=S(f32)
// LAYER=2: NCAT=256, blockIdx.y: 0=[K f32 | Q bf16], 1=[V bf16 | S f32]
template <int LAYER>
__global__ __launch_bounds__(256, 2) void gemm_kernel(const float* __restrict__ A,
                                                      const float* __restrict__ Bt,
                                                      const float* __restrict__ bias,
                                                      float* __restrict__ Kout,
                                                      float* __restrict__ Sout,
                                                      __hip_bfloat16* __restrict__ QVout,
                                                      int M) {
    constexpr int NCAT = (LAYER == 1) ? 512 : 256;
    __shared__ float As[128][68];
    __shared__ float Bs[64][132];
    const int tid = threadIdx.x;
    const int ty = tid >> 4, tx = tid & 15;
    const int row0 = blockIdx.x * 128;
    const int col0 = blockIdx.y * 128;

    float acc[8][8];
#pragma unroll
    for (int i = 0; i < 8; ++i)
#pragma unroll
        for (int j = 0; j < 8; ++j) acc[i][j] = 0.f;

    for (int k0 = 0; k0 < 128; k0 += 64) {
        __syncthreads();
#pragma unroll
        for (int i = 0; i < 8; ++i) {
            int idx = i * 256 + tid;
            int r = idx >> 4, c4 = idx & 15;
            int gr = row0 + r;
            float4 v = make_float4(0.f, 0.f, 0.f, 0.f);
            if (gr < M) v = *(const float4*)&A[(size_t)gr * 128 + k0 + c4 * 4];
            *(float4*)&As[r][c4 * 4] = v;
        }
#pragma unroll
        for (int i = 0; i < 8; ++i) {
            int idx = i * 256 + tid;
            int r = idx >> 5, c4 = idx & 31;
            float4 v = *(const float4*)&Bt[(size_t)(k0 + r) * NCAT + col0 + c4 * 4];
            *(float4*)&Bs[r][c4 * 4] = v;
        }
        __syncthreads();
#pragma unroll 4
        for (int k = 0; k < 64; ++k) {
            float a[8], b[8];
#pragma unroll
            for (int i = 0; i < 8; ++i) a[i] = As[16 * i + ty][k];
            float4 b0 = *(const float4*)&Bs[k][tx * 4];
            float4 b1 = *(const float4*)&Bs[k][64 + tx * 4];
            b[0] = b0.x; b[1] = b0.y; b[2] = b0.z; b[3] = b0.w;
            b[4] = b1.x; b[5] = b1.y; b[6] = b1.z; b[7] = b1.w;
#pragma unroll
            for (int i = 0; i < 8; ++i)
#pragma unroll
                for (int j = 0; j < 8; ++j) acc[i][j] += a[i] * b[j];
        }
    }
    // bias add
#pragma unroll
    for (int j = 0; j < 4; ++j) {
        float bj0 = bias[col0 + tx * 4 + j];
        float bj1 = bias[col0 + 64 + tx * 4 + j];
#pragma unroll
        for (int i = 0; i < 8; ++i) { acc[i][j] += bj0; acc[i][j + 4] += bj1; }
    }

    if (LAYER == 1) {
        if (blockIdx.y == 0 || blockIdx.y == 3) {
            float* O = (blockIdx.y == 0) ? Kout : Sout;
#pragma unroll
            for (int i = 0; i < 8; ++i) {
                int r = row0 + 16 * i + ty;
                if (r < M) {
                    float4 o0 = make_float4(acc[i][0], acc[i][1], acc[i][2], acc[i][3]);
                    float4 o1 = make_float4(acc[i][4], acc[i][5], acc[i][6], acc[i][7]);
                    *(float4*)&O[(size_t)r * 128 + tx * 4] = o0;
                    *(float4*)&O[(size_t)r * 128 + 64 + tx * 4] = o1;
                }
            }
        } else {
            int par = (blockIdx.y == 1) ? 0 : 1;
#pragma unroll
            for (int i = 0; i < 8; ++i) {
                int r = row0 + 16 * i + ty;
                if (r < M) {
#pragma unroll
                    for (int j = 0; j < 8; ++j) {
                        int c = (j < 4) ? (tx * 4 + j) : (64 + tx * 4 + (j - 4));
                        QVout[(size_t)r * 256 + 2 * c + par] = __float2bfloat16(acc[i][j]);
                    }
                }
            }
        }
    } else {
        if (blockIdx.y == 0) {   // cols 0..63 = K, 64..127 = Q
#pragma unroll
            for (int i = 0; i < 8; ++i) {
                int r = row0 + 16 * i + ty;
                if (r < M) {
                    float4 o0 = make_float4(acc[i][0], acc[i][1], acc[i][2], acc[i][3]);
                    *(float4*)&Kout[(size_t)r * 64 + tx * 4] = o0;
#pragma unroll
                    for (int j = 4; j < 8; ++j) {
                        int gc = tx * 4 + (j - 4);
                        QVout[(size_t)r * 128 + 2 * gc] = __float2bfloat16(acc[i][j]);
                    }
                }
            }
        } else {                 // cols 128..191 = V, 192..255 = S
#pragma unroll
            for (int i = 0; i < 8; ++i) {
                int r = row0 + 16 * i + ty;
                if (r < M) {
#pragma unroll
                    for (int j = 0; j < 4; ++j) {
                        int gc = tx * 4 + j;
                        QVout[(size_t)r * 128 + 2 * gc + 1] = __float2bfloat16(acc[i][j]);
                    }
                    float4 o1 = make_float4(acc[i][4], acc[i][5], acc[i][6], acc[i][7]);
                    *(float4*)&Sout[(size_t)r * 64 + tx * 4] = o1;
                }
            }
        }
    }
}

// ---------------- edge aggregation (gather mode) ----------------
// layer1: lane handles channels 2l,2l+1; one ushort4 (8B) gather per edge
__global__ __launch_bounds__(256) void edge1_kernel(const float* __restrict__ K1,
                                                    const float* __restrict__ S1,
                                                    const __hip_bfloat16* __restrict__ QV1,
                                                    const int* __restrict__ offs,
                                                    const int* __restrict__ esrc,
                                                    float* __restrict__ H1) {
    int node = blockIdx.x * 4 + (threadIdx.x >> 6);
    if (node >= N_NODES) return;
    int lane = threadIdx.x & 63;
    float2 k2 = *(const float2*)&K1[(size_t)node * 128 + lane * 2];
    float2 s2 = *(const float2*)&S1[(size_t)node * 128 + lane * 2];
    const unsigned short* QV = (const unsigned short*)QV1;
    float ax = 0.f, ay = 0.f;
    int e0 = offs[node], e1 = offs[node + 1];
    for (int j = e0; j < e1; ++j) {
        int s = esrc[j];
        ushort4 qv = *(const ushort4*)(QV + (size_t)s * 256 + lane * 4);
        float qx = bfu2f(qv.x), vx = bfu2f(qv.y);
        float qy = bfu2f(qv.z), vy = bfu2f(qv.w);
        float gx = 1.f / (1.f + __expf(-(k2.x + qx)));
        float gy = 1.f / (1.f + __expf(-(k2.y + qy)));
        ax += gx * vx;
        ay += gy * vy;
    }
    float rx = s2.x + ax, ry = s2.y + ay;
    float2 o;
    o.x = rx > 0.f ? rx : 0.f;
    o.y = ry > 0.f ? ry : 0.f;
    *(float2*)&H1[(size_t)node * 128 + lane * 2] = o;
}

// layer2: lane handles channel l; one ushort2 (4B) gather per edge
__global__ __launch_bounds__(256) void edge2_kernel(const float* __restrict__ K2,
                                                    const float* __restrict__ S2,
                                                    const __hip_bfloat16* __restrict__ QV2,
                                                    const int* __restrict__ offs,
                                                    const int* __restrict__ esrc,
                                                    float* __restrict__ H2) {
    int node = blockIdx.x * 4 + (threadIdx.x >> 6);
    if (node >= N_NODES) return;
    int lane = threadIdx.x & 63;
    float k1 = K2[(size_t)node * 64 + lane];
    float s1 = S2[(size_t)node * 64 + lane];
    const unsigned short* QV = (const unsigned short*)QV2;
    float a = 0.f;
    int e0 = offs[node], e1 = offs[node + 1];
    for (int j = e0; j < e1; ++j) {
        int s = esrc[j];
        ushort2 qv = *(const ushort2*)(QV + (size_t)s * 128 + lane * 2);
        float q = bfu2f(qv.x), v = bfu2f(qv.y);
        float g = 1.f / (1.f + __expf(-(k1 + q)));
        a += g * v;
    }
    float r = s1 + a;
    H2[(size_t)node * 64 + lane] = r > 0.f ? r : 0.f;
}

// ---------------- pooling ----------------
__global__ void bounds_kernel(const int* __restrict__ batch, int* __restrict__ sg,
                              int* __restrict__ eg) {
    int n = blockIdx.x * 256 + threadIdx.x;
    if (n >= N_NODES) return;
    int b = batch[n];
    if (n == 0) {
        sg[b] = 0;
    } else {
        int p = batch[n - 1];
        if (p != b) { sg[b] = n; eg[p] = n - 1; }
    }
    if (n == N_NODES - 1) eg[b] = N_NODES - 1;
}

__global__ void pool_kernel(const float* __restrict__ H2, const int* __restrict__ sg,
                            const int* __restrict__ eg, float* __restrict__ pooled) {
    int g = blockIdx.x;
    int s = sg[g], e = eg[g];
    int ch = threadIdx.x & 63, sub = threadIdx.x >> 6;
    float acc = 0.f;
    for (int n = s + sub; n <= e; n += 4) acc += H2[(size_t)n * 64 + ch];
    __shared__ float red[4][64];
    red[sub][ch] = acc;
    __syncthreads();
    if (sub == 0) {
        float v = red[0][ch] + red[1][ch] + red[2][ch] + red[3][ch];
        int cnt = e - s + 1;
        if (cnt < 1) cnt = 1;
        pooled[g * 64 + ch] = v / (float)cnt;
    }
}

__global__ void fc_kernel(const float* __restrict__ pooled, const float* __restrict__ wfc,
                          const float* __restrict__ bfc, float* __restrict__ out) {
    int t = threadIdx.x;          // 128
    int g = t >> 1, c = t & 1;
    float s = bfc[c];
#pragma unroll
    for (int i = 0; i < 64; ++i) s += pooled[g * 64 + i] * wfc[c * 64 + i];
    out[g * 2 + c] = s;
}

// ---------------- launch ----------------
extern "C" void kernel_launch(void* const* d_in, const int* in_sizes, int n_in,
                              void* d_out, int out_size, void* d_ws, size_t ws_size,
                              hipStream_t stream) {
    (void)in_sizes; (void)n_in; (void)out_size; (void)ws_size;
    const float* x    = (const float*)d_in[0];
    const int*   ei   = (const int*)d_in[1];
    const int*   batch= (const int*)d_in[2];
    const float* w1k = (const float*)d_in[3];  const float* b1k = (const float*)d_in[4];
    const float* w1q = (const float*)d_in[5];  const float* b1q = (const float*)d_in[6];
    const float* w1v = (const float*)d_in[7];  const float* b1v = (const float*)d_in[8];
    const float* w1s = (const float*)d_in[9];  const float* b1s = (const float*)d_in[10];
    const float* w2k = (const float*)d_in[11]; const float* b2k = (const float*)d_in[12];
    const float* w2q = (const float*)d_in[13]; const float* b2q = (const float*)d_in[14];
    const float* w2v = (const float*)d_in[15]; const float* b2v = (const float*)d_in[16];
    const float* w2s = (const float*)d_in[17]; const float* b2s = (const float*)d_in[18];
    const float* wfc = (const float*)d_in[19]; const float* bfc = (const float*)d_in[20];
    float* out = (float*)d_out;

    char* ws = (char*)d_ws;
    float* K1   = (float*)(ws + OFF_K1);
    float* S1   = (float*)(ws + OFF_S1);
    __hip_bfloat16* QV1 = (__hip_bfloat16*)(ws + OFF_QV1);
    float* H1   = (float*)(ws + OFF_H1);
    float* K2   = (float*)(ws + OFF_K2);
    float* S2   = (float*)(ws + OFF_S2);
    __hip_bfloat16* QV2 = (__hip_bfloat16*)(ws + OFF_QV2);
    float* H2   = (float*)(ws + OFF_H2);
    int*   esrc = (int*)(ws + OFF_ESRC);
    int*   offs = (int*)(ws + OFF_OFFS);
    int*   curs = (int*)(ws + OFF_CURS);
    float* Wt1  = (float*)(ws + OFF_WT1);
    float* bc1  = (float*)(ws + OFF_BC1);
    float* Wt2  = (float*)(ws + OFF_WT2);
    float* bc2  = (float*)(ws + OFF_BC2);
    int*   sg   = (int*)(ws + OFF_SG);
    int*   eg   = (int*)(ws + OFF_EG);
    float* pl   = (float*)(ws + OFF_PL);
    int*   bsum = (int*)(ws + OFF_BSUM);
    int*   bbas = (int*)(ws + OFF_BBAS);

    const int* src = ei;
    const int* dst = ei + N_EDGES;

    // weight prep
    prep1_kernel<<<256, 256, 0, stream>>>(w1k, b1k, w1q, b1q, w1v, b1v, w1s, b1s, Wt1, bc1);
    prep2_kernel<<<128, 256, 0, stream>>>(w2k, b2k, w2q, b2q, w2v, b2v, w2s, b2s, Wt2, bc2);

    // CSR build (by dst), hierarchical scan
    hipMemsetAsync(curs, 0, N_NODES * sizeof(int), stream);
    hist_kernel<<<(N_EDGES + 255) / 256, 256, 0, stream>>>(dst, curs);
    bsum_kernel<<<SCAN_BLOCKS, 256, 0, stream>>>(curs, bsum);
    bscan_kernel<<<1, 256, 0, stream>>>(bsum, bbas);
    offs_kernel<<<SCAN_BLOCKS, 256, 0, stream>>>(curs, bbas, offs, curs);
    fill_kernel<<<(N_EDGES + 255) / 256, 256, 0, stream>>>(src, dst, curs, esrc);

    // layer 1
    gemm_kernel<1><<<dim3(391, 4), 256, 0, stream>>>(x, Wt1, bc1, K1, S1, QV1, N_NODES);
    edge1_kernel<<<12500, 256, 0, stream>>>(K1, S1, QV1, offs, esrc, H1);

    // layer 2
    gemm_kernel<2><<<dim3(391, 2), 256, 0, stream>>>(H1, Wt2, bc2, K2, S2, QV2, N_NODES);
    edge2_kernel<<<12500, 256, 0, stream>>>(K2, S2, QV2, offs, esrc, H2);

    // pooling + fc
    hipMemsetAsync(sg, 0x7f, N_GRAPHS * sizeof(int), stream);
    hipMemsetAsync(eg, 0x80, N_GRAPHS * sizeof(int), stream);
    bounds_kernel<<<(N_NODES + 255) / 256, 256, 0, stream>>>(batch, sg, eg);
    pool_kernel<<<N_GRAPHS, 256, 0, stream>>>(H2, sg, eg, pl);
    fc_kernel<<<1, 128, 0, stream>>>(pl, wfc, bfc, out);
}

// Round 4
// 427.071 us; speedup vs baseline: 2.1990x; 1.1866x over previous
//
#include <hip/hip_runtime.h>
#include <hip/hip_bf16.h>
#include <math.h>

#define N_NODES 50000
#define N_EDGES 800000
#define N_GRAPHS 64
#define SCAN_BLOCKS 196   // ceil(50000/256)

typedef __attribute__((ext_vector_type(8))) short short8v;   // 8 bf16 (4 VGPRs)
typedef __attribute__((ext_vector_type(4))) float float4v;   // MFMA acc

// ---------------- workspace layout (bytes) ----------------
static constexpr size_t OFF_K1   = 0;            // f32 [50000][128] = 25.6 MB
static constexpr size_t OFF_S1   = 25600000;     // f32 [50000][128]
static constexpr size_t OFF_QV1  = 51200000;     // bf16 [50000][256] interleaved q,v
static constexpr size_t OFF_H1B  = 76800000;     // bf16 [50000][128] = 12.8 MB
static constexpr size_t OFF_XB   = 89600000;     // bf16 [50000][128] = 12.8 MB
// layer2 overlays layer1 buffers (K1/S1/QV1 dead after edge1):
static constexpr size_t OFF_K2   = 0;            // f32 [50000][64]
static constexpr size_t OFF_S2   = 12800000;     // f32 [50000][64]
static constexpr size_t OFF_QV2  = 25600000;     // bf16 [50000][128] interleaved
static constexpr size_t OFF_H2   = 38400000;     // f32 [50000][64]
static constexpr size_t OFF_ESRC = 102400000;    // 3.2 MB
static constexpr size_t OFF_OFFS = 105600000;    // 50001*4
static constexpr size_t OFF_CURS = 105800064;    // 50000*4 (hist, then cursor)
static constexpr size_t OFF_BP1  = 106000064;    // bf16 packed 128*512 = 131072 B
static constexpr size_t OFF_BC1  = 106131136;    // 512*4
static constexpr size_t OFF_BP2  = 106133184;    // bf16 packed 128*256 = 65536 B
static constexpr size_t OFF_BC2  = 106198720;    // 256*4
static constexpr size_t OFF_SG   = 106199744;
static constexpr size_t OFF_EG   = 106200000;
static constexpr size_t OFF_PL   = 106200256;    // 64*64*4
static constexpr size_t OFF_BSUM = 106216640;
static constexpr size_t OFF_BBAS = 106217664;

__device__ inline float bfu2f(unsigned short u) {
    union { unsigned int i; float f; } w;
    w.i = ((unsigned int)u) << 16;
    return w.f;
}
__device__ inline unsigned short f2bf(float f) {
    __hip_bfloat16 h = __float2bfloat16(f);
    union { __hip_bfloat16 h; unsigned short u; } cv;
    cv.h = h;
    return cv.u;
}

// ---------------- x -> bf16 cast ----------------
__global__ void cast_kernel(const float* __restrict__ x, unsigned short* __restrict__ xb) {
    int id = blockIdx.x * 256 + threadIdx.x;      // 800000 threads, 8 elems each
    float4 v0 = *(const float4*)&x[(size_t)id * 8];
    float4 v1 = *(const float4*)&x[(size_t)id * 8 + 4];
    short8v o;
    o[0] = (short)f2bf(v0.x); o[1] = (short)f2bf(v0.y);
    o[2] = (short)f2bf(v0.z); o[3] = (short)f2bf(v0.w);
    o[4] = (short)f2bf(v1.x); o[5] = (short)f2bf(v1.y);
    o[6] = (short)f2bf(v1.z); o[7] = (short)f2bf(v1.w);
    *(short8v*)(xb + (size_t)id * 8) = o;
}

// ---------------- weight prep: pack into MFMA B-fragment order ----------------
// Bp index: ((ct*4 + ks)*64 + lane)*8 + j  holds  B[k][c],
//   c = ct*16 + (lane&15), k = ks*32 + (lane>>4)*8 + j,  B[k][c] = W_g[n*128+k]
__global__ void prep1_kernel(const float* __restrict__ wk, const float* __restrict__ bk,
                             const float* __restrict__ wq, const float* __restrict__ bq,
                             const float* __restrict__ wv, const float* __restrict__ bv,
                             const float* __restrict__ ws, const float* __restrict__ bs,
                             unsigned short* __restrict__ Bp, float* __restrict__ bcat) {
    int id = blockIdx.x * 256 + threadIdx.x;      // 8192 total
    if (id < 8192) {
        int l = id & 63, ks = (id >> 6) & 3, ct = id >> 8;   // ct 0..31
        int c = ct * 16 + (l & 15);
        int g = c >> 7, n = c & 127;
        const float* W = (g == 0) ? wk : (g == 1) ? wq : (g == 2) ? wv : ws;
        int kb = ks * 32 + ((l >> 4) << 3);
        short8v o;
#pragma unroll
        for (int j = 0; j < 8; ++j) o[j] = (short)f2bf(W[n * 128 + kb + j]);
        *(short8v*)(Bp + (size_t)id * 8) = o;
    }
    if (id < 512) {
        int g = id >> 7, n = id & 127;
        const float* B = (g == 0) ? bk : (g == 1) ? bq : (g == 2) ? bv : bs;
        bcat[id] = B[n];
    }
}

__global__ void prep2_kernel(const float* __restrict__ wk, const float* __restrict__ bk,
                             const float* __restrict__ wq, const float* __restrict__ bq,
                             const float* __restrict__ wv, const float* __restrict__ bv,
                             const float* __restrict__ ws, const float* __restrict__ bs,
                             unsigned short* __restrict__ Bp, float* __restrict__ bcat) {
    int id = blockIdx.x * 256 + threadIdx.x;      // 4096 total
    if (id < 4096) {
        int l = id & 63, ks = (id >> 6) & 3, ct = id >> 8;   // ct 0..15
        int c = ct * 16 + (l & 15);
        int g = c >> 6, n = c & 63;
        const float* W = (g == 0) ? wk : (g == 1) ? wq : (g == 2) ? wv : ws;
        int kb = ks * 32 + ((l >> 4) << 3);
        short8v o;
#pragma unroll
        for (int j = 0; j < 8; ++j) o[j] = (short)f2bf(W[n * 128 + kb + j]);
        *(short8v*)(Bp + (size_t)id * 8) = o;
    }
    if (id < 256) {
        int g = id >> 6, n = id & 63;
        const float* B = (g == 0) ? bk : (g == 1) ? bq : (g == 2) ? bv : bs;
        bcat[id] = B[n];
    }
}

// ---------------- CSR build ----------------
__global__ void hist_kernel(const int* __restrict__ dst, int* __restrict__ hist) {
    int e = blockIdx.x * 256 + threadIdx.x;
    if (e < N_EDGES) atomicAdd(&hist[dst[e]], 1);
}

__global__ void bsum_kernel(const int* __restrict__ hist, int* __restrict__ bsum) {
    int t = threadIdx.x;
    int idx = blockIdx.x * 256 + t;
    __shared__ int sh[256];
    sh[t] = (idx < N_NODES) ? hist[idx] : 0;
    __syncthreads();
    for (int d = 128; d > 0; d >>= 1) {
        if (t < d) sh[t] += sh[t + d];
        __syncthreads();
    }
    if (t == 0) bsum[blockIdx.x] = sh[0];
}

__global__ void bscan_kernel(const int* __restrict__ bsum, int* __restrict__ bbase) {
    int t = threadIdx.x;   // 256
    __shared__ int sh[256];
    sh[t] = (t < SCAN_BLOCKS) ? bsum[t] : 0;
    __syncthreads();
    for (int d = 1; d < 256; d <<= 1) {
        int v = (t >= d) ? sh[t - d] : 0;
        __syncthreads();
        sh[t] += v;
        __syncthreads();
    }
    if (t < SCAN_BLOCKS) bbase[t] = (t == 0) ? 0 : sh[t - 1];
}

__global__ void offs_kernel(const int* __restrict__ hist, const int* __restrict__ bbase,
                            int* __restrict__ offs, int* __restrict__ cursor) {
    int t = threadIdx.x;
    int idx = blockIdx.x * 256 + t;
    int v = (idx < N_NODES) ? hist[idx] : 0;
    __shared__ int sh[256];
    sh[t] = v;
    __syncthreads();
    for (int d = 1; d < 256; d <<= 1) {
        int u = (t >= d) ? sh[t - d] : 0;
        __syncthreads();
        sh[t] += u;
        __syncthreads();
    }
    if (idx < N_NODES) {
        int o = bbase[blockIdx.x] + sh[t] - v;   // exclusive
        offs[idx] = o;
        cursor[idx] = o;
    }
    if (idx == 0) offs[N_NODES] = N_EDGES;
}

__global__ void fill_kernel(const int* __restrict__ src, const int* __restrict__ dst,
                            int* __restrict__ cursor, int* __restrict__ esrc) {
    int e = blockIdx.x * 256 + threadIdx.x;
    if (e < N_EDGES) {
        int d = dst[e];
        int pos = atomicAdd(&cursor[d], 1);
        esrc[pos] = src[e];
    }
}

// ---------------- bf16 MFMA GEMM: C[M,NCAT] = A[M,128] * B[128,NCAT] + bias ----------------
// A: bf16 [M][128] row-major (256B rows). B: packed fragment order (see prep).
// Tile 128x128, 4 waves; wave w owns rows 32w..32w+31 (m=0,1), all 8 col-16-blocks.
// A staged in LDS with 16B-chunk XOR swizzle: chunk c of row r stored at c^(r&7).
// Fragment maps (m89-verified): A lane l: row=l&15, k=(l>>4)*8+j.
//                               C/D lane l: col=l&15, row=(l>>4)*4+reg.
template <int LAYER>
__global__ __launch_bounds__(256) void gemm_mfma(const unsigned short* __restrict__ Ab,
                                                 const unsigned short* __restrict__ Bp,
                                                 const float* __restrict__ bias,
                                                 float* __restrict__ Kout,
                                                 float* __restrict__ Sout,
                                                 unsigned short* __restrict__ QVout,
                                                 int M) {
    __shared__ __align__(16) unsigned char As[32768];
    const int tid = threadIdx.x;
    const int w = tid >> 6, l = tid & 63;
    const int lx = l & 15, lg = l >> 4;
    const int row0 = blockIdx.x * 128;
    const int colb = blockIdx.y * 128;

    // stage A tile (128 rows x 128 bf16), swizzled chunks
#pragma unroll
    for (int i = 0; i < 8; ++i) {
        int id = i * 256 + tid;
        int r = id >> 4, c = id & 15;
        int gr = row0 + r;
        short8v v;
#pragma unroll
        for (int j = 0; j < 8; ++j) v[j] = 0;
        if (gr < M) v = *(const short8v*)(Ab + (size_t)gr * 128 + c * 8);
        *(short8v*)(As + r * 256 + ((c ^ (r & 7)) << 4)) = v;
    }
    __syncthreads();

    float4v acc[2][8];
#pragma unroll
    for (int m = 0; m < 2; ++m)
#pragma unroll
        for (int n = 0; n < 8; ++n)
#pragma unroll
            for (int q = 0; q < 4; ++q) acc[m][n][q] = 0.f;

    const int ct0 = blockIdx.y * 8;   // global col-tile base (16-col tiles)
#pragma unroll
    for (int ks = 0; ks < 4; ++ks) {
        short8v a[2];
#pragma unroll
        for (int m = 0; m < 2; ++m) {
            int rl = 32 * w + 16 * m + lx;
            int cc = ks * 4 + lg;
            a[m] = *(const short8v*)(As + rl * 256 + ((cc ^ (rl & 7)) << 4));
        }
#pragma unroll
        for (int n = 0; n < 8; ++n) {
            short8v b = *(const short8v*)(Bp + (size_t)(((ct0 + n) * 4 + ks) * 64 + l) * 8);
            acc[0][n] = __builtin_amdgcn_mfma_f32_16x16x32_bf16(a[0], b, acc[0][n], 0, 0, 0);
            acc[1][n] = __builtin_amdgcn_mfma_f32_16x16x32_bf16(a[1], b, acc[1][n], 0, 0, 0);
        }
    }

    float bb[8];
#pragma unroll
    for (int n = 0; n < 8; ++n) bb[n] = bias[colb + 16 * n + lx];

    const int rbase = row0 + 32 * w + 4 * lg;
#pragma unroll
    for (int m = 0; m < 2; ++m) {
#pragma unroll
        for (int reg = 0; reg < 4; ++reg) {
            int r = rbase + 16 * m + reg;
            if (r >= M) continue;
#pragma unroll
            for (int n = 0; n < 8; ++n) {
                float val = acc[m][n][reg] + bb[n];
                int c = 16 * n + lx;              // 0..127 within block cols
                if (LAYER == 1) {
                    if (blockIdx.y == 0)      Kout[(size_t)r * 128 + c] = val;
                    else if (blockIdx.y == 1) QVout[(size_t)r * 256 + 2 * c]     = f2bf(val);
                    else if (blockIdx.y == 2) QVout[(size_t)r * 256 + 2 * c + 1] = f2bf(val);
                    else                      Sout[(size_t)r * 128 + c] = val;
                } else {
                    if (blockIdx.y == 0) {
                        if (c < 64) Kout[(size_t)r * 64 + c] = val;
                        else        QVout[(size_t)r * 128 + 2 * (c - 64)] = f2bf(val);
                    } else {
                        if (c < 64) QVout[(size_t)r * 128 + 2 * c + 1] = f2bf(val);
                        else        Sout[(size_t)r * 64 + (c - 64)] = val;
                    }
                }
            }
        }
    }
}

// ---------------- edge aggregation (gather mode) ----------------
__global__ __launch_bounds__(256) void edge1_kernel(const float* __restrict__ K1,
                                                    const float* __restrict__ S1,
                                                    const unsigned short* __restrict__ QV,
                                                    const int* __restrict__ offs,
                                                    const int* __restrict__ esrc,
                                                    unsigned short* __restrict__ H1B) {
    int node = blockIdx.x * 4 + (threadIdx.x >> 6);
    if (node >= N_NODES) return;
    int lane = threadIdx.x & 63;
    float2 k2 = *(const float2*)&K1[(size_t)node * 128 + lane * 2];
    float2 s2 = *(const float2*)&S1[(size_t)node * 128 + lane * 2];
    float ax = 0.f, ay = 0.f;
    int e0 = offs[node], e1 = offs[node + 1];
    for (int j = e0; j < e1; ++j) {
        int s = esrc[j];
        ushort4 qv = *(const ushort4*)(QV + (size_t)s * 256 + lane * 4);
        float qx = bfu2f(qv.x), vx = bfu2f(qv.y);
        float qy = bfu2f(qv.z), vy = bfu2f(qv.w);
        float gx = 1.f / (1.f + __expf(-(k2.x + qx)));
        float gy = 1.f / (1.f + __expf(-(k2.y + qy)));
        ax += gx * vx;
        ay += gy * vy;
    }
    float rx = s2.x + ax, ry = s2.y + ay;
    ushort2 o;
    o.x = f2bf(rx > 0.f ? rx : 0.f);
    o.y = f2bf(ry > 0.f ? ry : 0.f);
    *(ushort2*)(H1B + (size_t)node * 128 + lane * 2) = o;
}

__global__ __launch_bounds__(256) void edge2_kernel(const float* __restrict__ K2,
                                                    const float* __restrict__ S2,
                                                    const unsigned short* __restrict__ QV,
                                                    const int* __restrict__ offs,
                                                    const int* __restrict__ esrc,
                                                    float* __restrict__ H2) {
    int node = blockIdx.x * 4 + (threadIdx.x >> 6);
    if (node >= N_NODES) return;
    int lane = threadIdx.x & 63;
    float k1 = K2[(size_t)node * 64 + lane];
    float s1 = S2[(size_t)node * 64 + lane];
    float a = 0.f;
    int e0 = offs[node], e1 = offs[node + 1];
    for (int j = e0; j < e1; ++j) {
        int s = esrc[j];
        ushort2 qv = *(const ushort2*)(QV + (size_t)s * 128 + lane * 2);
        float q = bfu2f(qv.x), v = bfu2f(qv.y);
        float g = 1.f / (1.f + __expf(-(k1 + q)));
        a += g * v;
    }
    float r = s1 + a;
    H2[(size_t)node * 64 + lane] = r > 0.f ? r : 0.f;
}

// ---------------- pooling ----------------
__global__ void bounds_kernel(const int* __restrict__ batch, int* __restrict__ sg,
                              int* __restrict__ eg) {
    int n = blockIdx.x * 256 + threadIdx.x;
    if (n >= N_NODES) return;
    int b = batch[n];
    if (n == 0) {
        sg[b] = 0;
    } else {
        int p = batch[n - 1];
        if (p != b) { sg[b] = n; eg[p] = n - 1; }
    }
    if (n == N_NODES - 1) eg[b] = N_NODES - 1;
}

__global__ void pool_kernel(const float* __restrict__ H2, const int* __restrict__ sg,
                            const int* __restrict__ eg, float* __restrict__ pooled) {
    int g = blockIdx.x;
    int s = sg[g], e = eg[g];
    int ch = threadIdx.x & 63, sub = threadIdx.x >> 6;
    float acc = 0.f;
    for (int n = s + sub; n <= e; n += 4) acc += H2[(size_t)n * 64 + ch];
    __shared__ float red[4][64];
    red[sub][ch] = acc;
    __syncthreads();
    if (sub == 0) {
        float v = red[0][ch] + red[1][ch] + red[2][ch] + red[3][ch];
        int cnt = e - s + 1;
        if (cnt < 1) cnt = 1;
        pooled[g * 64 + ch] = v / (float)cnt;
    }
}

__global__ void fc_kernel(const float* __restrict__ pooled, const float* __restrict__ wfc,
                          const float* __restrict__ bfc, float* __restrict__ out) {
    int t = threadIdx.x;          // 128
    int g = t >> 1, c = t & 1;
    float s = bfc[c];
#pragma unroll
    for (int i = 0; i < 64; ++i) s += pooled[g * 64 + i] * wfc[c * 64 + i];
    out[g * 2 + c] = s;
}

// ---------------- launch ----------------
extern "C" void kernel_launch(void* const* d_in, const int* in_sizes, int n_in,
                              void* d_out, int out_size, void* d_ws, size_t ws_size,
                              hipStream_t stream) {
    (void)in_sizes; (void)n_in; (void)out_size; (void)ws_size;
    const float* x    = (const float*)d_in[0];
    const int*   ei   = (const int*)d_in[1];
    const int*   batch= (const int*)d_in[2];
    const float* w1k = (const float*)d_in[3];  const float* b1k = (const float*)d_in[4];
    const float* w1q = (const float*)d_in[5];  const float* b1q = (const float*)d_in[6];
    const float* w1v = (const float*)d_in[7];  const float* b1v = (const float*)d_in[8];
    const float* w1s = (const float*)d_in[9];  const float* b1s = (const float*)d_in[10];
    const float* w2k = (const float*)d_in[11]; const float* b2k = (const float*)d_in[12];
    const float* w2q = (const float*)d_in[13]; const float* b2q = (const float*)d_in[14];
    const float* w2v = (const float*)d_in[15]; const float* b2v = (const float*)d_in[16];
    const float* w2s = (const float*)d_in[17]; const float* b2s = (const float*)d_in[18];
    const float* wfc = (const float*)d_in[19]; const float* bfc = (const float*)d_in[20];
    float* out = (float*)d_out;

    char* ws = (char*)d_ws;
    float* K1   = (float*)(ws + OFF_K1);
    float* S1   = (float*)(ws + OFF_S1);
    unsigned short* QV1 = (unsigned short*)(ws + OFF_QV1);
    unsigned short* H1B = (unsigned short*)(ws + OFF_H1B);
    unsigned short* XB  = (unsigned short*)(ws + OFF_XB);
    float* K2   = (float*)(ws + OFF_K2);
    float* S2   = (float*)(ws + OFF_S2);
    unsigned short* QV2 = (unsigned short*)(ws + OFF_QV2);
    float* H2   = (float*)(ws + OFF_H2);
    int*   esrc = (int*)(ws + OFF_ESRC);
    int*   offs = (int*)(ws + OFF_OFFS);
    int*   curs = (int*)(ws + OFF_CURS);
    unsigned short* BP1 = (unsigned short*)(ws + OFF_BP1);
    float* bc1  = (float*)(ws + OFF_BC1);
    unsigned short* BP2 = (unsigned short*)(ws + OFF_BP2);
    float* bc2  = (float*)(ws + OFF_BC2);
    int*   sg   = (int*)(ws + OFF_SG);
    int*   eg   = (int*)(ws + OFF_EG);
    float* pl   = (float*)(ws + OFF_PL);
    int*   bsum = (int*)(ws + OFF_BSUM);
    int*   bbas = (int*)(ws + OFF_BBAS);

    const int* src = ei;
    const int* dst = ei + N_EDGES;

    // prep: weight pack + bias concat + x cast
    prep1_kernel<<<32, 256, 0, stream>>>(w1k, b1k, w1q, b1q, w1v, b1v, w1s, b1s, BP1, bc1);
    prep2_kernel<<<16, 256, 0, stream>>>(w2k, b2k, w2q, b2q, w2v, b2v, w2s, b2s, BP2, bc2);
    cast_kernel<<<3125, 256, 0, stream>>>(x, XB);

    // CSR build (by dst), hierarchical scan
    hipMemsetAsync(curs, 0, N_NODES * sizeof(int), stream);
    hist_kernel<<<(N_EDGES + 255) / 256, 256, 0, stream>>>(dst, curs);
    bsum_kernel<<<SCAN_BLOCKS, 256, 0, stream>>>(curs, bsum);
    bscan_kernel<<<1, 256, 0, stream>>>(bsum, bbas);
    offs_kernel<<<SCAN_BLOCKS, 256, 0, stream>>>(curs, bbas, offs, curs);
    fill_kernel<<<(N_EDGES + 255) / 256, 256, 0, stream>>>(src, dst, curs, esrc);

    // layer 1
    gemm_mfma<1><<<dim3(391, 4), 256, 0, stream>>>(XB, BP1, bc1, K1, S1, QV1, N_NODES);
    edge1_kernel<<<12500, 256, 0, stream>>>(K1, S1, QV1, offs, esrc, H1B);

    // layer 2
    gemm_mfma<2><<<dim3(391, 2), 256, 0, stream>>>(H1B, BP2, bc2, K2, S2, QV2, N_NODES);
    edge2_kernel<<<12500, 256, 0, stream>>>(K2, S2, QV2, offs, esrc, H2);

    // pooling + fc
    hipMemsetAsync(sg, 0x7f, N_GRAPHS * sizeof(int), stream);
    hipMemsetAsync(eg, 0x80, N_GRAPHS * sizeof(int), stream);
    bounds_kernel<<<(N_NODES + 255) / 256, 256, 0, stream>>>(batch, sg, eg);
    pool_kernel<<<N_GRAPHS, 256, 0, stream>>>(H2, sg, eg, pl);
    fc_kernel<<<1, 128, 0, stream>>>(pl, wfc, bfc, out);
}

// Round 5
// 372.609 us; speedup vs baseline: 2.5204x; 1.1462x over previous
//
#include <hip/hip_runtime.h>
#include <hip/hip_bf16.h>
#include <math.h>

#define N_NODES 50000
#define N_EDGES 800000
#define N_GRAPHS 64
#define NCHUNK_SHIFT 13            // src chunk = src >> 13  (0..6)
#define NBUCK (N_NODES * 8)        // key = dst*8 | chunk
#define SB2 1563                   // ceil(400000/256)

typedef __attribute__((ext_vector_type(8))) short short8v;   // 8 bf16 (4 VGPRs)
typedef __attribute__((ext_vector_type(4))) float float4v;   // MFMA acc

// ---------------- workspace layout (bytes) ----------------
static constexpr size_t OFF_K1   = 0;            // f32 [50000][128] (pre-scaled by -log2e)
static constexpr size_t OFF_S1   = 25600000;     // f32 [50000][128]
static constexpr size_t OFF_QV1  = 51200000;     // bf16 [50000][256] interleaved q',v
static constexpr size_t OFF_H1B  = 76800000;     // bf16 [50000][128]
static constexpr size_t OFF_XB   = 89600000;     // bf16 [50000][128]
// layer2 overlays layer1 buffers (K1/S1/QV1 dead after edge1):
static constexpr size_t OFF_K2   = 0;            // f32 [50000][64] (pre-scaled)
static constexpr size_t OFF_S2   = 12800000;     // f32 [50000][64]
static constexpr size_t OFF_QV2  = 25600000;     // bf16 [50000][128] interleaved
static constexpr size_t OFF_H2   = 38400000;     // f32 [50000][64]
static constexpr size_t OFF_ESRC = 102400000;    // 3.2 MB (src-chunk-ordered per dst)
static constexpr size_t OFF_BOFF = 105600000;    // (NBUCK+1)*4 = 1,600,004 -> pad
static constexpr size_t OFF_BCUR = 107200512;    // NBUCK*4 (hist, then cursor)
static constexpr size_t OFF_BSUM = 108800512;    // SB2*4
static constexpr size_t OFF_BBAS = 108806912;    // SB2*4
static constexpr size_t OFF_BP1  = 108813312;    // bf16 packed 128*512
static constexpr size_t OFF_BC1  = 108944384;    // 512*4
static constexpr size_t OFF_BP2  = 108946432;    // bf16 packed 128*256
static constexpr size_t OFF_BC2  = 109011968;    // 256*4
static constexpr size_t OFF_SG   = 109012992;
static constexpr size_t OFF_EG   = 109013248;
static constexpr size_t OFF_PL   = 109013504;    // 64*64*4

#define NLOG2E 1.44269504f   // gate uses exp2(-(k+q)*log2e); sign folded into stores

__device__ inline unsigned short f2bf(float f) {
    __hip_bfloat16 h = __float2bfloat16(f);
    union { __hip_bfloat16 h; unsigned short u; } cv;
    cv.h = h;
    return cv.u;
}
__device__ inline float fast_exp2(float x) { float r; asm("v_exp_f32 %0, %1" : "=v"(r) : "v"(x)); return r; }
__device__ inline float fast_rcp (float x) { float r; asm("v_rcp_f32 %0, %1" : "=v"(r) : "v"(x)); return r; }
__device__ inline float u2f(unsigned int u) { union { unsigned int i; float f; } w; w.i = u; return w.f; }

// ---------------- x -> bf16 cast ----------------
__global__ void cast_kernel(const float* __restrict__ x, unsigned short* __restrict__ xb) {
    int id = blockIdx.x * 256 + threadIdx.x;
    float4 v0 = *(const float4*)&x[(size_t)id * 8];
    float4 v1 = *(const float4*)&x[(size_t)id * 8 + 4];
    short8v o;
    o[0] = (short)f2bf(v0.x); o[1] = (short)f2bf(v0.y);
    o[2] = (short)f2bf(v0.z); o[3] = (short)f2bf(v0.w);
    o[4] = (short)f2bf(v1.x); o[5] = (short)f2bf(v1.y);
    o[6] = (short)f2bf(v1.z); o[7] = (short)f2bf(v1.w);
    *(short8v*)(xb + (size_t)id * 8) = o;
}

// ---------------- weight prep: pack into MFMA B-fragment order ----------------
__global__ void prep1_kernel(const float* __restrict__ wk, const float* __restrict__ bk,
                             const float* __restrict__ wq, const float* __restrict__ bq,
                             const float* __restrict__ wv, const float* __restrict__ bv,
                             const float* __restrict__ ws, const float* __restrict__ bs,
                             unsigned short* __restrict__ Bp, float* __restrict__ bcat) {
    int id = blockIdx.x * 256 + threadIdx.x;      // 8192 total
    if (id < 8192) {
        int l = id & 63, ks = (id >> 6) & 3, ct = id >> 8;
        int c = ct * 16 + (l & 15);
        int g = c >> 7, n = c & 127;
        const float* W = (g == 0) ? wk : (g == 1) ? wq : (g == 2) ? wv : ws;
        int kb = ks * 32 + ((l >> 4) << 3);
        short8v o;
#pragma unroll
        for (int j = 0; j < 8; ++j) o[j] = (short)f2bf(W[n * 128 + kb + j]);
        *(short8v*)(Bp + (size_t)id * 8) = o;
    }
    if (id < 512) {
        int g = id >> 7, n = id & 127;
        const float* B = (g == 0) ? bk : (g == 1) ? bq : (g == 2) ? bv : bs;
        bcat[id] = B[n];
    }
}

__global__ void prep2_kernel(const float* __restrict__ wk, const float* __restrict__ bk,
                             const float* __restrict__ wq, const float* __restrict__ bq,
                             const float* __restrict__ wv, const float* __restrict__ bv,
                             const float* __restrict__ ws, const float* __restrict__ bs,
                             unsigned short* __restrict__ Bp, float* __restrict__ bcat) {
    int id = blockIdx.x * 256 + threadIdx.x;      // 4096 total
    if (id < 4096) {
        int l = id & 63, ks = (id >> 6) & 3, ct = id >> 8;
        int c = ct * 16 + (l & 15);
        int g = c >> 6, n = c & 63;
        const float* W = (g == 0) ? wk : (g == 1) ? wq : (g == 2) ? wv : ws;
        int kb = ks * 32 + ((l >> 4) << 3);
        short8v o;
#pragma unroll
        for (int j = 0; j < 8; ++j) o[j] = (short)f2bf(W[n * 128 + kb + j]);
        *(short8v*)(Bp + (size_t)id * 8) = o;
    }
    if (id < 256) {
        int g = id >> 6, n = id & 63;
        const float* B = (g == 0) ? bk : (g == 1) ? bq : (g == 2) ? bv : bs;
        bcat[id] = B[n];
    }
}

// ---------------- bucketed CSR build: key = dst*8 | (src>>13) ----------------
__global__ void hist2_kernel(const int* __restrict__ src, const int* __restrict__ dst,
                             int* __restrict__ hist) {
    int e = blockIdx.x * 256 + threadIdx.x;
    if (e < N_EDGES) {
        int key = (dst[e] << 3) | (src[e] >> NCHUNK_SHIFT);
        atomicAdd(&hist[key], 1);
    }
}

__global__ void bsum2_kernel(const int* __restrict__ hist, int* __restrict__ bsum) {
    int t = threadIdx.x;
    int idx = blockIdx.x * 256 + t;
    __shared__ int sh[256];
    sh[t] = (idx < NBUCK) ? hist[idx] : 0;
    __syncthreads();
    for (int d = 128; d > 0; d >>= 1) {
        if (t < d) sh[t] += sh[t + d];
        __syncthreads();
    }
    if (t == 0) bsum[blockIdx.x] = sh[0];
}

__global__ void bscan2_kernel(const int* __restrict__ bsum, int* __restrict__ bbase) {
    __shared__ int sh[1024];
    int t = threadIdx.x;   // 1024
    int a0 = (2 * t < SB2) ? bsum[2 * t] : 0;
    int a1 = (2 * t + 1 < SB2) ? bsum[2 * t + 1] : 0;
    sh[t] = a0 + a1;
    __syncthreads();
    for (int d = 1; d < 1024; d <<= 1) {
        int v = (t >= d) ? sh[t - d] : 0;
        __syncthreads();
        sh[t] += v;
        __syncthreads();
    }
    int base = (t == 0) ? 0 : sh[t - 1];
    if (2 * t < SB2) bbase[2 * t] = base;
    if (2 * t + 1 < SB2) bbase[2 * t + 1] = base + a0;
}

__global__ void offs2_kernel(const int* __restrict__ hist, const int* __restrict__ bbase,
                             int* __restrict__ offs, int* __restrict__ cursor) {
    int t = threadIdx.x;
    int idx = blockIdx.x * 256 + t;
    int v = (idx < NBUCK) ? hist[idx] : 0;
    __shared__ int sh[256];
    sh[t] = v;
    __syncthreads();
    for (int d = 1; d < 256; d <<= 1) {
        int u = (t >= d) ? sh[t - d] : 0;
        __syncthreads();
        sh[t] += u;
        __syncthreads();
    }
    if (idx < NBUCK) {
        int o = bbase[blockIdx.x] + sh[t] - v;   // exclusive
        offs[idx] = o;
        cursor[idx] = o;                          // cursor aliases hist: per-index RAW only
    }
    if (idx == 0) offs[NBUCK] = N_EDGES;
}

__global__ void fill2_kernel(const int* __restrict__ src, const int* __restrict__ dst,
                             int* __restrict__ cursor, int* __restrict__ esrc) {
    int e = blockIdx.x * 256 + threadIdx.x;
    if (e < N_EDGES) {
        int s = src[e];
        int key = (dst[e] << 3) | (s >> NCHUNK_SHIFT);
        int pos = atomicAdd(&cursor[key], 1);
        esrc[pos] = s;
    }
}

// ---------------- bf16 MFMA GEMM with split epilogue ----------------
// K and Q outputs pre-scaled by -log2e (gate = rcp(1+exp2(k'+q'))).
template <int LAYER>
__global__ __launch_bounds__(256) void gemm_mfma(const unsigned short* __restrict__ Ab,
                                                 const unsigned short* __restrict__ Bp,
                                                 const float* __restrict__ bias,
                                                 float* __restrict__ Kout,
                                                 float* __restrict__ Sout,
                                                 unsigned short* __restrict__ QVout,
                                                 int M) {
    __shared__ __align__(16) unsigned char As[32768];
    const int tid = threadIdx.x;
    const int w = tid >> 6, l = tid & 63;
    const int lx = l & 15, lg = l >> 4;
    const int row0 = blockIdx.x * 128;
    const int colb = blockIdx.y * 128;

#pragma unroll
    for (int i = 0; i < 8; ++i) {
        int id = i * 256 + tid;
        int r = id >> 4, c = id & 15;
        int gr = row0 + r;
        short8v v;
#pragma unroll
        for (int j = 0; j < 8; ++j) v[j] = 0;
        if (gr < M) v = *(const short8v*)(Ab + (size_t)gr * 128 + c * 8);
        *(short8v*)(As + r * 256 + ((c ^ (r & 7)) << 4)) = v;
    }
    __syncthreads();

    float4v acc[2][8];
#pragma unroll
    for (int m = 0; m < 2; ++m)
#pragma unroll
        for (int n = 0; n < 8; ++n)
#pragma unroll
            for (int q = 0; q < 4; ++q) acc[m][n][q] = 0.f;

    const int ct0 = blockIdx.y * 8;
#pragma unroll
    for (int ks = 0; ks < 4; ++ks) {
        short8v a[2];
#pragma unroll
        for (int m = 0; m < 2; ++m) {
            int rl = 32 * w + 16 * m + lx;
            int cc = ks * 4 + lg;
            a[m] = *(const short8v*)(As + rl * 256 + ((cc ^ (rl & 7)) << 4));
        }
#pragma unroll
        for (int n = 0; n < 8; ++n) {
            short8v b = *(const short8v*)(Bp + (size_t)(((ct0 + n) * 4 + ks) * 64 + l) * 8);
            acc[0][n] = __builtin_amdgcn_mfma_f32_16x16x32_bf16(a[0], b, acc[0][n], 0, 0, 0);
            acc[1][n] = __builtin_amdgcn_mfma_f32_16x16x32_bf16(a[1], b, acc[1][n], 0, 0, 0);
        }
    }

    float bb[8];
#pragma unroll
    for (int n = 0; n < 8; ++n) bb[n] = bias[colb + 16 * n + lx];

    const int rbase = row0 + 32 * w + 4 * lg;
#pragma unroll
    for (int m = 0; m < 2; ++m) {
#pragma unroll
        for (int reg = 0; reg < 4; ++reg) {
            int r = rbase + 16 * m + reg;
            if (r >= M) continue;
#pragma unroll
            for (int n = 0; n < 8; ++n) {
                float val = acc[m][n][reg] + bb[n];
                int c = 16 * n + lx;
                if (LAYER == 1) {
                    if (blockIdx.y == 0)      Kout[(size_t)r * 128 + c] = -NLOG2E * val;
                    else if (blockIdx.y == 1) QVout[(size_t)r * 256 + 2 * c]     = f2bf(-NLOG2E * val);
                    else if (blockIdx.y == 2) QVout[(size_t)r * 256 + 2 * c + 1] = f2bf(val);
                    else                      Sout[(size_t)r * 128 + c] = val;
                } else {
                    if (blockIdx.y == 0) {
                        if (c < 64) Kout[(size_t)r * 64 + c] = -NLOG2E * val;
                        else        QVout[(size_t)r * 128 + 2 * (c - 64)] = f2bf(-NLOG2E * val);
                    } else {
                        if (c < 64) QVout[(size_t)r * 128 + 2 * c + 1] = f2bf(val);
                        else        Sout[(size_t)r * 64 + (c - 64)] = val;
                    }
                }
            }
        }
    }
}

// ---------------- edge aggregation (gather, wave-uniform scalar loop) ----------------
__global__ __launch_bounds__(256) void edge1_kernel(const float* __restrict__ K1,
                                                    const float* __restrict__ S1,
                                                    const unsigned int* __restrict__ QV,
                                                    const int* __restrict__ boffs,
                                                    const int* __restrict__ esrc,
                                                    unsigned short* __restrict__ H1B) {
    int node = __builtin_amdgcn_readfirstlane(blockIdx.x * 4 + (threadIdx.x >> 6));
    int lane = threadIdx.x & 63;
    float2 k2 = *(const float2*)&K1[(size_t)node * 128 + lane * 2];   // pre-scaled -log2e*(k)
    float2 s2 = *(const float2*)&S1[(size_t)node * 128 + lane * 2];
    float ax = 0.f, ay = 0.f;
    int e0 = boffs[node * 8], e1 = boffs[node * 8 + 8];
    for (int j = e0; j < e1; ++j) {
        int s = esrc[j];
        uint2 qv = *(const uint2*)(QV + (size_t)s * 128 + lane * 2);
        float q0 = u2f(qv.x << 16);
        float v0 = u2f(qv.x & 0xffff0000u);
        float q1 = u2f(qv.y << 16);
        float v1 = u2f(qv.y & 0xffff0000u);
        float ex = fast_exp2(k2.x + q0);
        float ey = fast_exp2(k2.y + q1);
        ax += v0 * fast_rcp(1.f + ex);
        ay += v1 * fast_rcp(1.f + ey);
    }
    float rx = s2.x + ax, ry = s2.y + ay;
    ushort2 o;
    o.x = f2bf(rx > 0.f ? rx : 0.f);
    o.y = f2bf(ry > 0.f ? ry : 0.f);
    *(ushort2*)(H1B + (size_t)node * 128 + lane * 2) = o;
}

__global__ __launch_bounds__(256) void edge2_kernel(const float* __restrict__ K2,
                                                    const float* __restrict__ S2,
                                                    const unsigned int* __restrict__ QV,
                                                    const int* __restrict__ boffs,
                                                    const int* __restrict__ esrc,
                                                    float* __restrict__ H2) {
    int node = __builtin_amdgcn_readfirstlane(blockIdx.x * 4 + (threadIdx.x >> 6));
    int lane = threadIdx.x & 63;
    float k1 = K2[(size_t)node * 64 + lane];     // pre-scaled
    float s1 = S2[(size_t)node * 64 + lane];
    float a = 0.f;
    int e0 = boffs[node * 8], e1 = boffs[node * 8 + 8];
    for (int j = e0; j < e1; ++j) {
        int s = esrc[j];
        unsigned int qv = QV[(size_t)s * 64 + lane];
        float q = u2f(qv << 16);
        float v = u2f(qv & 0xffff0000u);
        float e = fast_exp2(k1 + q);
        a += v * fast_rcp(1.f + e);
    }
    float r = s1 + a;
    H2[(size_t)node * 64 + lane] = r > 0.f ? r : 0.f;
}

// ---------------- pooling ----------------
__global__ void bounds_kernel(const int* __restrict__ batch, int* __restrict__ sg,
                              int* __restrict__ eg) {
    int n = blockIdx.x * 256 + threadIdx.x;
    if (n >= N_NODES) return;
    int b = batch[n];
    if (n == 0) {
        sg[b] = 0;
    } else {
        int p = batch[n - 1];
        if (p != b) { sg[b] = n; eg[p] = n - 1; }
    }
    if (n == N_NODES - 1) eg[b] = N_NODES - 1;
}

__global__ void pool_kernel(const float* __restrict__ H2, const int* __restrict__ sg,
                            const int* __restrict__ eg, float* __restrict__ pooled) {
    int g = blockIdx.x;
    int s = sg[g], e = eg[g];
    int ch = threadIdx.x & 63, sub = threadIdx.x >> 6;
    float acc = 0.f;
    for (int n = s + sub; n <= e; n += 4) acc += H2[(size_t)n * 64 + ch];
    __shared__ float red[4][64];
    red[sub][ch] = acc;
    __syncthreads();
    if (sub == 0) {
        float v = red[0][ch] + red[1][ch] + red[2][ch] + red[3][ch];
        int cnt = e - s + 1;
        if (cnt < 1) cnt = 1;
        pooled[g * 64 + ch] = v / (float)cnt;
    }
}

__global__ void fc_kernel(const float* __restrict__ pooled, const float* __restrict__ wfc,
                          const float* __restrict__ bfc, float* __restrict__ out) {
    int t = threadIdx.x;          // 128
    int g = t >> 1, c = t & 1;
    float s = bfc[c];
#pragma unroll
    for (int i = 0; i < 64; ++i) s += pooled[g * 64 + i] * wfc[c * 64 + i];
    out[g * 2 + c] = s;
}

// ---------------- launch ----------------
extern "C" void kernel_launch(void* const* d_in, const int* in_sizes, int n_in,
                              void* d_out, int out_size, void* d_ws, size_t ws_size,
                              hipStream_t stream) {
    (void)in_sizes; (void)n_in; (void)out_size; (void)ws_size;
    const float* x    = (const float*)d_in[0];
    const int*   ei   = (const int*)d_in[1];
    const int*   batch= (const int*)d_in[2];
    const float* w1k = (const float*)d_in[3];  const float* b1k = (const float*)d_in[4];
    const float* w1q = (const float*)d_in[5];  const float* b1q = (const float*)d_in[6];
    const float* w1v = (const float*)d_in[7];  const float* b1v = (const float*)d_in[8];
    const float* w1s = (const float*)d_in[9];  const float* b1s = (const float*)d_in[10];
    const float* w2k = (const float*)d_in[11]; const float* b2k = (const float*)d_in[12];
    const float* w2q = (const float*)d_in[13]; const float* b2q = (const float*)d_in[14];
    const float* w2v = (const float*)d_in[15]; const float* b2v = (const float*)d_in[16];
    const float* w2s = (const float*)d_in[17]; const float* b2s = (const float*)d_in[18];
    const float* wfc = (const float*)d_in[19]; const float* bfc = (const float*)d_in[20];
    float* out = (float*)d_out;

    char* ws = (char*)d_ws;
    float* K1   = (float*)(ws + OFF_K1);
    float* S1   = (float*)(ws + OFF_S1);
    unsigned short* QV1 = (unsigned short*)(ws + OFF_QV1);
    unsigned short* H1B = (unsigned short*)(ws + OFF_H1B);
    unsigned short* XB  = (unsigned short*)(ws + OFF_XB);
    float* K2   = (float*)(ws + OFF_K2);
    float* S2   = (float*)(ws + OFF_S2);
    unsigned short* QV2 = (unsigned short*)(ws + OFF_QV2);
    float* H2   = (float*)(ws + OFF_H2);
    int*   esrc = (int*)(ws + OFF_ESRC);
    int*   boff = (int*)(ws + OFF_BOFF);
    int*   bcur = (int*)(ws + OFF_BCUR);
    int*   bsum = (int*)(ws + OFF_BSUM);
    int*   bbas = (int*)(ws + OFF_BBAS);
    unsigned short* BP1 = (unsigned short*)(ws + OFF_BP1);
    float* bc1  = (float*)(ws + OFF_BC1);
    unsigned short* BP2 = (unsigned short*)(ws + OFF_BP2);
    float* bc2  = (float*)(ws + OFF_BC2);
    int*   sg   = (int*)(ws + OFF_SG);
    int*   eg   = (int*)(ws + OFF_EG);
    float* pl   = (float*)(ws + OFF_PL);

    const int* src = ei;
    const int* dst = ei + N_EDGES;

    // prep
    prep1_kernel<<<32, 256, 0, stream>>>(w1k, b1k, w1q, b1q, w1v, b1v, w1s, b1s, BP1, bc1);
    prep2_kernel<<<16, 256, 0, stream>>>(w2k, b2k, w2q, b2q, w2v, b2v, w2s, b2s, BP2, bc2);
    cast_kernel<<<3125, 256, 0, stream>>>(x, XB);

    // bucketed CSR build (dst-major, src-chunk-minor)
    hipMemsetAsync(bcur, 0, NBUCK * sizeof(int), stream);
    hist2_kernel<<<(N_EDGES + 255) / 256, 256, 0, stream>>>(src, dst, bcur);
    bsum2_kernel<<<SB2, 256, 0, stream>>>(bcur, bsum);
    bscan2_kernel<<<1, 1024, 0, stream>>>(bsum, bbas);
    offs2_kernel<<<SB2, 256, 0, stream>>>(bcur, bbas, boff, bcur);
    fill2_kernel<<<(N_EDGES + 255) / 256, 256, 0, stream>>>(src, dst, bcur, esrc);

    // layer 1
    gemm_mfma<1><<<dim3(391, 4), 256, 0, stream>>>(XB, BP1, bc1, K1, S1, QV1, N_NODES);
    edge1_kernel<<<12500, 256, 0, stream>>>(K1, S1, (const unsigned int*)QV1, boff, esrc, H1B);

    // layer 2
    gemm_mfma<2><<<dim3(391, 2), 256, 0, stream>>>(H1B, BP2, bc2, K2, S2, QV2, N_NODES);
    edge2_kernel<<<12500, 256, 0, stream>>>(K2, S2, (const unsigned int*)QV2, boff, esrc, H2);

    // pooling + fc
    hipMemsetAsync(sg, 0x7f, N_GRAPHS * sizeof(int), stream);
    hipMemsetAsync(eg, 0x80, N_GRAPHS * sizeof(int), stream);
    bounds_kernel<<<(N_NODES + 255) / 256, 256, 0, stream>>>(batch, sg, eg);
    pool_kernel<<<N_GRAPHS, 256, 0, stream>>>(H2, sg, eg, pl);
    fc_kernel<<<1, 128, 0, stream>>>(pl, wfc, bfc, out);
}

// Round 6
// 335.698 us; speedup vs baseline: 2.7975x; 1.1100x over previous
//
#include <hip/hip_runtime.h>
#include <hip/hip_bf16.h>
#include <math.h>

#define N_NODES 50000
#define N_EDGES 800000
#define N_GRAPHS 64
#define SCAN_BLOCKS 196   // ceil(50000/256)

typedef __attribute__((ext_vector_type(8))) short short8v;   // 8 bf16 (4 VGPRs)
typedef __attribute__((ext_vector_type(4))) float float4v;   // MFMA acc

// ---------------- workspace layout (bytes) ----------------
static constexpr size_t OFF_K1   = 0;            // bf16 [50000][128] (pre-scaled -log2e) 12.8MB
static constexpr size_t OFF_S1   = 12800000;     // bf16 [50000][128]
static constexpr size_t OFF_QV1  = 25600000;     // bf16 [50000][256] interleaved q',v  25.6MB
static constexpr size_t OFF_H1B  = 51200000;     // bf16 [50000][128]
static constexpr size_t OFF_XB   = 64000000;     // bf16 [50000][128]
// layer2 overlays layer1 buffers (K1/S1/QV1 dead after edge1):
static constexpr size_t OFF_K2   = 0;            // bf16 [50000][64] (pre-scaled)
static constexpr size_t OFF_S2   = 6400000;      // bf16 [50000][64]
static constexpr size_t OFF_QV2  = 12800000;     // bf16 [50000][128] interleaved
static constexpr size_t OFF_H2   = 25600000;     // f32 [50000][64]
static constexpr size_t OFF_ESRC = 76800000;     // 3.2 MB
static constexpr size_t OFF_OFFS = 80000000;     // 50001*4 -> pad
static constexpr size_t OFF_CURS = 80200064;     // 50000*4 (hist, then cursor)
static constexpr size_t OFF_BSUM = 80400064;     // 196*4
static constexpr size_t OFF_BBAS = 80400848;
static constexpr size_t OFF_BP1  = 80401664;     // bf16 packed 128*512
static constexpr size_t OFF_BC1  = 80532736;     // 512*4
static constexpr size_t OFF_BP2  = 80534784;     // bf16 packed 128*256
static constexpr size_t OFF_BC2  = 80600320;     // 256*4
static constexpr size_t OFF_SG   = 80601344;
static constexpr size_t OFF_EG   = 80601600;
static constexpr size_t OFF_PL   = 80601856;     // 64*64*4

#define NLOG2E 1.44269504f   // gate = rcp(1 + exp2(k' + q')), k'/q' pre-scaled by -log2e

__device__ inline unsigned short f2bf(float f) {
    __hip_bfloat16 h = __float2bfloat16(f);
    union { __hip_bfloat16 h; unsigned short u; } cv;
    cv.h = h;
    return cv.u;
}
__device__ inline float fast_exp2(float x) { float r; asm("v_exp_f32 %0, %1" : "=v"(r) : "v"(x)); return r; }
__device__ inline float fast_rcp (float x) { float r; asm("v_rcp_f32 %0, %1" : "=v"(r) : "v"(x)); return r; }
__device__ inline float u2f(unsigned int u) { union { unsigned int i; float f; } w; w.i = u; return w.f; }

// accumulate one edge's channel pair: qv = [q' lo | v hi]
__device__ inline void gacc2(uint2 qv, float kx, float ky, float& ax, float& ay) {
    float q0 = u2f(qv.x << 16), v0 = u2f(qv.x & 0xffff0000u);
    float q1 = u2f(qv.y << 16), v1 = u2f(qv.y & 0xffff0000u);
    ax += v0 * fast_rcp(1.f + fast_exp2(kx + q0));
    ay += v1 * fast_rcp(1.f + fast_exp2(ky + q1));
}
__device__ inline void gacc1(unsigned int qv, float k, float& a) {
    float q = u2f(qv << 16), v = u2f(qv & 0xffff0000u);
    a += v * fast_rcp(1.f + fast_exp2(k + q));
}

// ---------------- x -> bf16 cast ----------------
__global__ void cast_kernel(const float* __restrict__ x, unsigned short* __restrict__ xb) {
    int id = blockIdx.x * 256 + threadIdx.x;
    float4 v0 = *(const float4*)&x[(size_t)id * 8];
    float4 v1 = *(const float4*)&x[(size_t)id * 8 + 4];
    short8v o;
    o[0] = (short)f2bf(v0.x); o[1] = (short)f2bf(v0.y);
    o[2] = (short)f2bf(v0.z); o[3] = (short)f2bf(v0.w);
    o[4] = (short)f2bf(v1.x); o[5] = (short)f2bf(v1.y);
    o[6] = (short)f2bf(v1.z); o[7] = (short)f2bf(v1.w);
    *(short8v*)(xb + (size_t)id * 8) = o;
}

// ---------------- weight prep: pack into MFMA B-fragment order ----------------
__global__ void prep1_kernel(const float* __restrict__ wk, const float* __restrict__ bk,
                             const float* __restrict__ wq, const float* __restrict__ bq,
                             const float* __restrict__ wv, const float* __restrict__ bv,
                             const float* __restrict__ ws, const float* __restrict__ bs,
                             unsigned short* __restrict__ Bp, float* __restrict__ bcat) {
    int id = blockIdx.x * 256 + threadIdx.x;      // 8192 total
    if (id < 8192) {
        int l = id & 63, ks = (id >> 6) & 3, ct = id >> 8;
        int c = ct * 16 + (l & 15);
        int g = c >> 7, n = c & 127;
        const float* W = (g == 0) ? wk : (g == 1) ? wq : (g == 2) ? wv : ws;
        int kb = ks * 32 + ((l >> 4) << 3);
        short8v o;
#pragma unroll
        for (int j = 0; j < 8; ++j) o[j] = (short)f2bf(W[n * 128 + kb + j]);
        *(short8v*)(Bp + (size_t)id * 8) = o;
    }
    if (id < 512) {
        int g = id >> 7, n = id & 127;
        const float* B = (g == 0) ? bk : (g == 1) ? bq : (g == 2) ? bv : bs;
        bcat[id] = B[n];
    }
}

__global__ void prep2_kernel(const float* __restrict__ wk, const float* __restrict__ bk,
                             const float* __restrict__ wq, const float* __restrict__ bq,
                             const float* __restrict__ wv, const float* __restrict__ bv,
                             const float* __restrict__ ws, const float* __restrict__ bs,
                             unsigned short* __restrict__ Bp, float* __restrict__ bcat) {
    int id = blockIdx.x * 256 + threadIdx.x;      // 4096 total
    if (id < 4096) {
        int l = id & 63, ks = (id >> 6) & 3, ct = id >> 8;
        int c = ct * 16 + (l & 15);
        int g = c >> 6, n = c & 63;
        const float* W = (g == 0) ? wk : (g == 1) ? wq : (g == 2) ? wv : ws;
        int kb = ks * 32 + ((l >> 4) << 3);
        short8v o;
#pragma unroll
        for (int j = 0; j < 8; ++j) o[j] = (short)f2bf(W[n * 128 + kb + j]);
        *(short8v*)(Bp + (size_t)id * 8) = o;
    }
    if (id < 256) {
        int g = id >> 6, n = id & 63;
        const float* B = (g == 0) ? bk : (g == 1) ? bq : (g == 2) ? bv : bs;
        bcat[id] = B[n];
    }
}

// ---------------- CSR build (plain dst buckets) ----------------
__global__ void hist_kernel(const int* __restrict__ dst, int* __restrict__ hist) {
    int e = blockIdx.x * 256 + threadIdx.x;
    if (e < N_EDGES) atomicAdd(&hist[dst[e]], 1);
}

__global__ void bsum_kernel(const int* __restrict__ hist, int* __restrict__ bsum) {
    int t = threadIdx.x;
    int idx = blockIdx.x * 256 + t;
    __shared__ int sh[256];
    sh[t] = (idx < N_NODES) ? hist[idx] : 0;
    __syncthreads();
    for (int d = 128; d > 0; d >>= 1) {
        if (t < d) sh[t] += sh[t + d];
        __syncthreads();
    }
    if (t == 0) bsum[blockIdx.x] = sh[0];
}

__global__ void bscan_kernel(const int* __restrict__ bsum, int* __restrict__ bbase) {
    int t = threadIdx.x;   // 256
    __shared__ int sh[256];
    sh[t] = (t < SCAN_BLOCKS) ? bsum[t] : 0;
    __syncthreads();
    for (int d = 1; d < 256; d <<= 1) {
        int v = (t >= d) ? sh[t - d] : 0;
        __syncthreads();
        sh[t] += v;
        __syncthreads();
    }
    if (t < SCAN_BLOCKS) bbase[t] = (t == 0) ? 0 : sh[t - 1];
}

__global__ void offs_kernel(const int* __restrict__ hist, const int* __restrict__ bbase,
                            int* __restrict__ offs, int* __restrict__ cursor) {
    int t = threadIdx.x;
    int idx = blockIdx.x * 256 + t;
    int v = (idx < N_NODES) ? hist[idx] : 0;
    __shared__ int sh[256];
    sh[t] = v;
    __syncthreads();
    for (int d = 1; d < 256; d <<= 1) {
        int u = (t >= d) ? sh[t - d] : 0;
        __syncthreads();
        sh[t] += u;
        __syncthreads();
    }
    if (idx < N_NODES) {
        int o = bbase[blockIdx.x] + sh[t] - v;   // exclusive
        offs[idx] = o;
        cursor[idx] = o;                          // cursor aliases hist: per-index RAW only
    }
    if (idx == 0) offs[N_NODES] = N_EDGES;
}

__global__ void fill_kernel(const int* __restrict__ src, const int* __restrict__ dst,
                            int* __restrict__ cursor, int* __restrict__ esrc) {
    int e = blockIdx.x * 256 + threadIdx.x;
    if (e < N_EDGES) {
        int d = dst[e];
        int pos = atomicAdd(&cursor[d], 1);
        esrc[pos] = src[e];
    }
}

// ---------------- bf16 MFMA GEMM with split epilogue (all outputs bf16) ----------------
// K and Q outputs pre-scaled by -log2e.
template <int LAYER>
__global__ __launch_bounds__(256) void gemm_mfma(const unsigned short* __restrict__ Ab,
                                                 const unsigned short* __restrict__ Bp,
                                                 const float* __restrict__ bias,
                                                 unsigned short* __restrict__ Kout,
                                                 unsigned short* __restrict__ Sout,
                                                 unsigned short* __restrict__ QVout,
                                                 int M) {
    __shared__ __align__(16) unsigned char As[32768];
    const int tid = threadIdx.x;
    const int w = tid >> 6, l = tid & 63;
    const int lx = l & 15, lg = l >> 4;
    const int row0 = blockIdx.x * 128;
    const int colb = blockIdx.y * 128;

#pragma unroll
    for (int i = 0; i < 8; ++i) {
        int id = i * 256 + tid;
        int r = id >> 4, c = id & 15;
        int gr = row0 + r;
        short8v v;
#pragma unroll
        for (int j = 0; j < 8; ++j) v[j] = 0;
        if (gr < M) v = *(const short8v*)(Ab + (size_t)gr * 128 + c * 8);
        *(short8v*)(As + r * 256 + ((c ^ (r & 7)) << 4)) = v;
    }
    __syncthreads();

    float4v acc[2][8];
#pragma unroll
    for (int m = 0; m < 2; ++m)
#pragma unroll
        for (int n = 0; n < 8; ++n)
#pragma unroll
            for (int q = 0; q < 4; ++q) acc[m][n][q] = 0.f;

    const int ct0 = blockIdx.y * 8;
#pragma unroll
    for (int ks = 0; ks < 4; ++ks) {
        short8v a[2];
#pragma unroll
        for (int m = 0; m < 2; ++m) {
            int rl = 32 * w + 16 * m + lx;
            int cc = ks * 4 + lg;
            a[m] = *(const short8v*)(As + rl * 256 + ((cc ^ (rl & 7)) << 4));
        }
#pragma unroll
        for (int n = 0; n < 8; ++n) {
            short8v b = *(const short8v*)(Bp + (size_t)(((ct0 + n) * 4 + ks) * 64 + l) * 8);
            acc[0][n] = __builtin_amdgcn_mfma_f32_16x16x32_bf16(a[0], b, acc[0][n], 0, 0, 0);
            acc[1][n] = __builtin_amdgcn_mfma_f32_16x16x32_bf16(a[1], b, acc[1][n], 0, 0, 0);
        }
    }

    float bb[8];
#pragma unroll
    for (int n = 0; n < 8; ++n) bb[n] = bias[colb + 16 * n + lx];

    const int rbase = row0 + 32 * w + 4 * lg;
#pragma unroll
    for (int m = 0; m < 2; ++m) {
#pragma unroll
        for (int reg = 0; reg < 4; ++reg) {
            int r = rbase + 16 * m + reg;
            if (r >= M) continue;
#pragma unroll
            for (int n = 0; n < 8; ++n) {
                float val = acc[m][n][reg] + bb[n];
                int c = 16 * n + lx;
                if (LAYER == 1) {
                    if (blockIdx.y == 0)      Kout[(size_t)r * 128 + c] = f2bf(-NLOG2E * val);
                    else if (blockIdx.y == 1) QVout[(size_t)r * 256 + 2 * c]     = f2bf(-NLOG2E * val);
                    else if (blockIdx.y == 2) QVout[(size_t)r * 256 + 2 * c + 1] = f2bf(val);
                    else                      Sout[(size_t)r * 128 + c] = f2bf(val);
                } else {
                    if (blockIdx.y == 0) {
                        if (c < 64) Kout[(size_t)r * 64 + c] = f2bf(-NLOG2E * val);
                        else        QVout[(size_t)r * 128 + 2 * (c - 64)] = f2bf(-NLOG2E * val);
                    } else {
                        if (c < 64) QVout[(size_t)r * 128 + 2 * c + 1] = f2bf(val);
                        else        Sout[(size_t)r * 64 + (c - 64)] = f2bf(val);
                    }
                }
            }
        }
    }
}

// ---------------- edge aggregation (gather, scalar loop, unroll-4 MLP) ----------------
__global__ __launch_bounds__(256) void edge1_kernel(const unsigned short* __restrict__ K1b,
                                                    const unsigned short* __restrict__ S1b,
                                                    const unsigned int* __restrict__ QV,
                                                    const int* __restrict__ offs,
                                                    const int* __restrict__ esrc,
                                                    unsigned short* __restrict__ H1B) {
    int node = __builtin_amdgcn_readfirstlane(blockIdx.x * 4 + (threadIdx.x >> 6));
    int lane = threadIdx.x & 63;
    unsigned int kr = *(const unsigned int*)(K1b + (size_t)node * 128 + lane * 2);
    unsigned int sr = *(const unsigned int*)(S1b + (size_t)node * 128 + lane * 2);
    float kx = u2f(kr << 16), ky = u2f(kr & 0xffff0000u);
    float sx = u2f(sr << 16), sy = u2f(sr & 0xffff0000u);
    float ax0 = 0.f, ay0 = 0.f, ax1 = 0.f, ay1 = 0.f;
    float ax2 = 0.f, ay2 = 0.f, ax3 = 0.f, ay3 = 0.f;
    int e0 = offs[node], e1 = offs[node + 1];
    int j = e0;
    for (; j + 4 <= e1; j += 4) {
        int s0 = esrc[j], s1 = esrc[j + 1], s2 = esrc[j + 2], s3 = esrc[j + 3];
        uint2 a = *(const uint2*)(QV + (size_t)s0 * 128 + lane * 2);
        uint2 b = *(const uint2*)(QV + (size_t)s1 * 128 + lane * 2);
        uint2 c = *(const uint2*)(QV + (size_t)s2 * 128 + lane * 2);
        uint2 d = *(const uint2*)(QV + (size_t)s3 * 128 + lane * 2);
        gacc2(a, kx, ky, ax0, ay0);
        gacc2(b, kx, ky, ax1, ay1);
        gacc2(c, kx, ky, ax2, ay2);
        gacc2(d, kx, ky, ax3, ay3);
    }
    for (; j < e1; ++j) {
        uint2 a = *(const uint2*)(QV + (size_t)esrc[j] * 128 + lane * 2);
        gacc2(a, kx, ky, ax0, ay0);
    }
    float rx = sx + (ax0 + ax1) + (ax2 + ax3);
    float ry = sy + (ay0 + ay1) + (ay2 + ay3);
    ushort2 o;
    o.x = f2bf(rx > 0.f ? rx : 0.f);
    o.y = f2bf(ry > 0.f ? ry : 0.f);
    *(ushort2*)(H1B + (size_t)node * 128 + lane * 2) = o;
}

__global__ __launch_bounds__(256) void edge2_kernel(const unsigned short* __restrict__ K2b,
                                                    const unsigned short* __restrict__ S2b,
                                                    const unsigned int* __restrict__ QV,
                                                    const int* __restrict__ offs,
                                                    const int* __restrict__ esrc,
                                                    float* __restrict__ H2) {
    int node = __builtin_amdgcn_readfirstlane(blockIdx.x * 4 + (threadIdx.x >> 6));
    int lane = threadIdx.x & 63;
    float k1 = u2f(((unsigned int)K2b[(size_t)node * 64 + lane]) << 16);
    float s1 = u2f(((unsigned int)S2b[(size_t)node * 64 + lane]) << 16);
    float a0 = 0.f, a1 = 0.f, a2 = 0.f, a3 = 0.f;
    int e0 = offs[node], e1 = offs[node + 1];
    int j = e0;
    for (; j + 4 <= e1; j += 4) {
        unsigned int qa = QV[(size_t)esrc[j] * 64 + lane];
        unsigned int qb = QV[(size_t)esrc[j + 1] * 64 + lane];
        unsigned int qc = QV[(size_t)esrc[j + 2] * 64 + lane];
        unsigned int qd = QV[(size_t)esrc[j + 3] * 64 + lane];
        gacc1(qa, k1, a0);
        gacc1(qb, k1, a1);
        gacc1(qc, k1, a2);
        gacc1(qd, k1, a3);
    }
    for (; j < e1; ++j) gacc1(QV[(size_t)esrc[j] * 64 + lane], k1, a0);
    float r = s1 + (a0 + a1) + (a2 + a3);
    H2[(size_t)node * 64 + lane] = r > 0.f ? r : 0.f;
}

// ---------------- pooling ----------------
__global__ void bounds_kernel(const int* __restrict__ batch, int* __restrict__ sg,
                              int* __restrict__ eg) {
    int n = blockIdx.x * 256 + threadIdx.x;
    if (n >= N_NODES) return;
    int b = batch[n];
    if (n == 0) {
        sg[b] = 0;
    } else {
        int p = batch[n - 1];
        if (p != b) { sg[b] = n; eg[p] = n - 1; }
    }
    if (n == N_NODES - 1) eg[b] = N_NODES - 1;
}

__global__ void pool_kernel(const float* __restrict__ H2, const int* __restrict__ sg,
                            const int* __restrict__ eg, float* __restrict__ pooled) {
    int g = blockIdx.x;
    int s = sg[g], e = eg[g];
    int ch = threadIdx.x & 63, sub = threadIdx.x >> 6;
    float acc = 0.f;
    for (int n = s + sub; n <= e; n += 4) acc += H2[(size_t)n * 64 + ch];
    __shared__ float red[4][64];
    red[sub][ch] = acc;
    __syncthreads();
    if (sub == 0) {
        float v = red[0][ch] + red[1][ch] + red[2][ch] + red[3][ch];
        int cnt = e - s + 1;
        if (cnt < 1) cnt = 1;
        pooled[g * 64 + ch] = v / (float)cnt;
    }
}

__global__ void fc_kernel(const float* __restrict__ pooled, const float* __restrict__ wfc,
                          const float* __restrict__ bfc, float* __restrict__ out) {
    int t = threadIdx.x;          // 128
    int g = t >> 1, c = t & 1;
    float s = bfc[c];
#pragma unroll
    for (int i = 0; i < 64; ++i) s += pooled[g * 64 + i] * wfc[c * 64 + i];
    out[g * 2 + c] = s;
}

// ---------------- launch ----------------
extern "C" void kernel_launch(void* const* d_in, const int* in_sizes, int n_in,
                              void* d_out, int out_size, void* d_ws, size_t ws_size,
                              hipStream_t stream) {
    (void)in_sizes; (void)n_in; (void)out_size; (void)ws_size;
    const float* x    = (const float*)d_in[0];
    const int*   ei   = (const int*)d_in[1];
    const int*   batch= (const int*)d_in[2];
    const float* w1k = (const float*)d_in[3];  const float* b1k = (const float*)d_in[4];
    const float* w1q = (const float*)d_in[5];  const float* b1q = (const float*)d_in[6];
    const float* w1v = (const float*)d_in[7];  const float* b1v = (const float*)d_in[8];
    const float* w1s = (const float*)d_in[9];  const float* b1s = (const float*)d_in[10];
    const float* w2k = (const float*)d_in[11]; const float* b2k = (const float*)d_in[12];
    const float* w2q = (const float*)d_in[13]; const float* b2q = (const float*)d_in[14];
    const float* w2v = (const float*)d_in[15]; const float* b2v = (const float*)d_in[16];
    const float* w2s = (const float*)d_in[17]; const float* b2s = (const float*)d_in[18];
    const float* wfc = (const float*)d_in[19]; const float* bfc = (const float*)d_in[20];
    float* out = (float*)d_out;

    char* ws = (char*)d_ws;
    unsigned short* K1  = (unsigned short*)(ws + OFF_K1);
    unsigned short* S1  = (unsigned short*)(ws + OFF_S1);
    unsigned short* QV1 = (unsigned short*)(ws + OFF_QV1);
    unsigned short* H1B = (unsigned short*)(ws + OFF_H1B);
    unsigned short* XB  = (unsigned short*)(ws + OFF_XB);
    unsigned short* K2  = (unsigned short*)(ws + OFF_K2);
    unsigned short* S2  = (unsigned short*)(ws + OFF_S2);
    unsigned short* QV2 = (unsigned short*)(ws + OFF_QV2);
    float* H2   = (float*)(ws + OFF_H2);
    int*   esrc = (int*)(ws + OFF_ESRC);
    int*   offs = (int*)(ws + OFF_OFFS);
    int*   curs = (int*)(ws + OFF_CURS);
    int*   bsum = (int*)(ws + OFF_BSUM);
    int*   bbas = (int*)(ws + OFF_BBAS);
    unsigned short* BP1 = (unsigned short*)(ws + OFF_BP1);
    float* bc1  = (float*)(ws + OFF_BC1);
    unsigned short* BP2 = (unsigned short*)(ws + OFF_BP2);
    float* bc2  = (float*)(ws + OFF_BC2);
    int*   sg   = (int*)(ws + OFF_SG);
    int*   eg   = (int*)(ws + OFF_EG);
    float* pl   = (float*)(ws + OFF_PL);

    const int* src = ei;
    const int* dst = ei + N_EDGES;

    // prep
    prep1_kernel<<<32, 256, 0, stream>>>(w1k, b1k, w1q, b1q, w1v, b1v, w1s, b1s, BP1, bc1);
    prep2_kernel<<<16, 256, 0, stream>>>(w2k, b2k, w2q, b2q, w2v, b2v, w2s, b2s, BP2, bc2);
    cast_kernel<<<3125, 256, 0, stream>>>(x, XB);

    // CSR build (by dst), hierarchical scan
    hipMemsetAsync(curs, 0, N_NODES * sizeof(int), stream);
    hist_kernel<<<(N_EDGES + 255) / 256, 256, 0, stream>>>(dst, curs);
    bsum_kernel<<<SCAN_BLOCKS, 256, 0, stream>>>(curs, bsum);
    bscan_kernel<<<1, 256, 0, stream>>>(bsum, bbas);
    offs_kernel<<<SCAN_BLOCKS, 256, 0, stream>>>(curs, bbas, offs, curs);
    fill_kernel<<<(N_EDGES + 255) / 256, 256, 0, stream>>>(src, dst, curs, esrc);

    // layer 1
    gemm_mfma<1><<<dim3(391, 4), 256, 0, stream>>>(XB, BP1, bc1, K1, S1, QV1, N_NODES);
    edge1_kernel<<<12500, 256, 0, stream>>>(K1, S1, (const unsigned int*)QV1, offs, esrc, H1B);

    // layer 2
    gemm_mfma<2><<<dim3(391, 2), 256, 0, stream>>>(H1B, BP2, bc2, K2, S2, QV2, N_NODES);
    edge2_kernel<<<12500, 256, 0, stream>>>(K2, S2, (const unsigned int*)QV2, offs, esrc, H2);

    // pooling + fc
    hipMemsetAsync(sg, 0x7f, N_GRAPHS * sizeof(int), stream);
    hipMemsetAsync(eg, 0x80, N_GRAPHS * sizeof(int), stream);
    bounds_kernel<<<(N_NODES + 255) / 256, 256, 0, stream>>>(batch, sg, eg);
    pool_kernel<<<N_GRAPHS, 256, 0, stream>>>(H2, sg, eg, pl);
    fc_kernel<<<1, 128, 0, stream>>>(pl, wfc, bfc, out);
}